// Round 2
// baseline (3360.939 us; speedup 1.0000x reference)
//
#include <hip/hip_runtime.h>
#include <stdint.h>

typedef unsigned short u16;
typedef unsigned int u32;

#define B_ 32
#define C_ 256
#define S_ 1024

__device__ __forceinline__ float bf2f(u16 u){ return __uint_as_float(((u32)u)<<16); }
__device__ __forceinline__ u16 f2bf(float f){
    u32 x = __float_as_uint(f);
    u32 r = (x + 0x7fffu + ((x>>16)&1u)) >> 16;
    return (u16)r;
}
__device__ __forceinline__ float lo16(u32 u){ return __uint_as_float(u<<16); }
__device__ __forceinline__ float hi16(u32 u){ return __uint_as_float(u & 0xffff0000u); }
__device__ __forceinline__ u32 pack2(float a, float b){ return (u32)f2bf(a) | ((u32)f2bf(b)<<16); }

template<bool BF16>
__device__ __forceinline__ float ldT(const void* p, size_t i){
    if constexpr (BF16) return bf2f(((const u16*)p)[i]);
    else return ((const float*)p)[i];
}
template<bool BF16>
__device__ __forceinline__ void stT(void* p, size_t i, float v){
    if constexpr (BF16) ((u16*)p)[i] = f2bf(v);
    else ((float*)p)[i] = v;
}

// ---------------------------------------------------------------------------
// Dtype detector: vote on low u16 of first 256 words of lidar.
// bf16 data -> low half is a bf16 ~N(0,1): exponent in [117,131] ~99.9%.
// fp32 data -> low half is mantissa bits: ~6% land in that band.
// flag: 1 = bf16, 0 = fp32
// ---------------------------------------------------------------------------
__global__ __launch_bounds__(256) void k_detect(const u32* __restrict__ w, int* __restrict__ flag){
    u32 v = w[threadIdx.x];
    int e = (v >> 7) & 0xff;   // exponent field of low-half bf16
    int plaus = (e >= 117 && e <= 131) ? 1 : 0;
    __shared__ int cnt;
    if (threadIdx.x == 0) cnt = 0;
    __syncthreads();
    atomicAdd(&cnt, plaus);
    __syncthreads();
    if (threadIdx.x == 0) *flag = (cnt > 128) ? 1 : 0;
}

// ---------------------------------------------------------------------------
// Router
// ---------------------------------------------------------------------------
template<bool BF16>
__global__ __launch_bounds__(256) void k_router(
    const int* __restrict__ flag,
    const void* __restrict__ lidar, const void* __restrict__ hsi,
    const void* __restrict__ w1, const void* __restrict__ b1,
    const void* __restrict__ w2, const void* __restrict__ b2,
    void* __restrict__ out)   // path_prob written at element offset 8388608
{
    if (*flag != (BF16 ? 1 : 0)) return;
    int b = blockIdx.x;
    int tid = threadIdx.x;
    int wave = tid >> 6, lane = tid & 63;
    __shared__ float sg[512];
    __shared__ float sh[128];
    for (int row = wave; row < 512; row += 4){
        const void* src = (row < 256) ? lidar : hsi;
        size_t base = (size_t)b*C_*S_ + (size_t)(row & 255)*S_;
        float acc = 0.f;
        for (int k = lane; k < S_; k += 64) acc += ldT<BF16>(src, base + k);
        #pragma unroll
        for (int off = 32; off > 0; off >>= 1) acc += __shfl_down(acc, off, 64);
        if (lane == 0) sg[row] = acc * (1.0f/1024.0f);
    }
    __syncthreads();
    if (tid < 128){
        float a = ldT<BF16>(b1, tid);
        size_t wb = (size_t)tid*512;
        for (int k = 0; k < 512; ++k) a += sg[k]*ldT<BF16>(w1, wb + k);
        sh[tid] = fmaxf(a, 0.f);
    }
    __syncthreads();
    if (tid < 4){
        float a = ldT<BF16>(b2, tid);
        size_t wb = (size_t)tid*128;
        for (int k = 0; k < 128; ++k) a += sh[k]*ldT<BF16>(w2, wb + k);
        stT<BF16>(out, (size_t)8388608 + b*4 + tid, 1.f/(1.f+expf(-a)));
    }
}

// ---------------------------------------------------------------------------
// QKV projections.  combo: 0=Q_l 1=K_l 2=V_l 3=Q_h 4=K_h 5=V_h
// Out_sm[b][s][o] = sum_c W[o][c] * In_cm[b][c][s] + bias[o]
// Q/K written fp32 (score precision), V written bf16.
// ---------------------------------------------------------------------------
template<bool BF16>
__global__ __launch_bounds__(256) void k_qkv(
    const int* __restrict__ flag,
    const void* __restrict__ lidar, const void* __restrict__ hsi,
    const void* __restrict__ Wq, const void* __restrict__ bq,
    const void* __restrict__ Wk, const void* __restrict__ bk,
    const void* __restrict__ Wv, const void* __restrict__ bv,
    float* __restrict__ Ql, float* __restrict__ Kl,
    float* __restrict__ Qh, float* __restrict__ Kh,
    u16* __restrict__ Vl, u16* __restrict__ Vh)
{
    if (*flag != (BF16 ? 1 : 0)) return;
    int z = blockIdx.z;
    int combo = z >> 5, b = z & 31;
    int ww = combo % 3;
    const void* in = (combo < 3) ? lidar : hsi;
    size_t inb = (size_t)b*C_*S_;
    const void* W    = (ww==0) ? Wq : (ww==1) ? Wk : Wv;
    const void* bias = (ww==0) ? bq : (ww==1) ? bk : bv;
    int s0 = blockIdx.x*64, o0 = blockIdx.y*64;
    int tid = threadIdx.x;
    __shared__ float sW[32][68];   // [c][o]
    __shared__ float sI[32][68];   // [c][s]
    float acc[4][4] = {};
    int o4 = (tid>>4)<<2, s4 = (tid&15)<<2;
    for (int c0 = 0; c0 < 256; c0 += 32){
        __syncthreads();
        if constexpr (BF16){
            int w_o = tid>>2, w_c = (tid&3)<<3;
            uint4 v = *(const uint4*)((const u16*)W + (size_t)(o0+w_o)*256 + c0 + w_c);
            sW[w_c+0][w_o]=lo16(v.x); sW[w_c+1][w_o]=hi16(v.x);
            sW[w_c+2][w_o]=lo16(v.y); sW[w_c+3][w_o]=hi16(v.y);
            sW[w_c+4][w_o]=lo16(v.z); sW[w_c+5][w_o]=hi16(v.z);
            sW[w_c+6][w_o]=lo16(v.w); sW[w_c+7][w_o]=hi16(v.w);
            int i_c = tid>>3, i_s = (tid&7)<<3;
            uint4 u = *(const uint4*)((const u16*)in + inb + (size_t)(c0+i_c)*S_ + s0 + i_s);
            sI[i_c][i_s+0]=lo16(u.x); sI[i_c][i_s+1]=hi16(u.x);
            sI[i_c][i_s+2]=lo16(u.y); sI[i_c][i_s+3]=hi16(u.y);
            sI[i_c][i_s+4]=lo16(u.z); sI[i_c][i_s+5]=hi16(u.z);
            sI[i_c][i_s+6]=lo16(u.w); sI[i_c][i_s+7]=hi16(u.w);
        } else {
            const float* Wf = (const float*)W;
            const float* inf_ = (const float*)in + inb;
            int w_o = tid>>2, w_c = (tid&3)<<3;
            float4 a0 = *(const float4*)(Wf + (size_t)(o0+w_o)*256 + c0 + w_c);
            float4 a1 = *(const float4*)(Wf + (size_t)(o0+w_o)*256 + c0 + w_c + 4);
            sW[w_c+0][w_o]=a0.x; sW[w_c+1][w_o]=a0.y; sW[w_c+2][w_o]=a0.z; sW[w_c+3][w_o]=a0.w;
            sW[w_c+4][w_o]=a1.x; sW[w_c+5][w_o]=a1.y; sW[w_c+6][w_o]=a1.z; sW[w_c+7][w_o]=a1.w;
            int i_c = tid>>4, i_s = (tid&15)<<2;
            *(float4*)&sI[i_c][i_s]    = *(const float4*)(inf_ + (size_t)(c0+i_c)*S_ + s0 + i_s);
            *(float4*)&sI[i_c+16][i_s] = *(const float4*)(inf_ + (size_t)(c0+i_c+16)*S_ + s0 + i_s);
        }
        __syncthreads();
        #pragma unroll 8
        for (int c = 0; c < 32; ++c){
            float4 a  = *(const float4*)&sW[c][o4];
            float4 bb = *(const float4*)&sI[c][s4];
            acc[0][0]+=a.x*bb.x; acc[0][1]+=a.x*bb.y; acc[0][2]+=a.x*bb.z; acc[0][3]+=a.x*bb.w;
            acc[1][0]+=a.y*bb.x; acc[1][1]+=a.y*bb.y; acc[1][2]+=a.y*bb.z; acc[1][3]+=a.y*bb.w;
            acc[2][0]+=a.z*bb.x; acc[2][1]+=a.z*bb.y; acc[2][2]+=a.z*bb.z; acc[2][3]+=a.z*bb.w;
            acc[3][0]+=a.w*bb.x; acc[3][1]+=a.w*bb.y; acc[3][2]+=a.w*bb.z; acc[3][3]+=a.w*bb.w;
        }
    }
    float bi[4];
    #pragma unroll
    for (int i = 0; i < 4; ++i) bi[i] = ldT<BF16>(bias, o0+o4+i);
    if (ww == 2){
        u16* O = ((combo==2)?Vl:Vh) + (size_t)b*S_*C_;
        #pragma unroll
        for (int j = 0; j < 4; ++j){
            u32 p0 = pack2(acc[0][j]+bi[0], acc[1][j]+bi[1]);
            u32 p1 = pack2(acc[2][j]+bi[2], acc[3][j]+bi[3]);
            *(uint2*)(O + (size_t)(s0+s4+j)*256 + o0+o4) = make_uint2(p0,p1);
        }
    } else {
        float* O = (combo==0)?Ql:(combo==1)?Kl:(combo==3)?Qh:Kh;
        O += (size_t)b*S_*C_;
        #pragma unroll
        for (int j = 0; j < 4; ++j){
            float4 v = make_float4(acc[0][j]+bi[0], acc[1][j]+bi[1], acc[2][j]+bi[2], acc[3][j]+bi[3]);
            *(float4*)(O + (size_t)(s0+s4+j)*256 + o0+o4) = v;
        }
    }
}

// ---------------------------------------------------------------------------
// QV1 = Q_l .* V_h ; QV2 = Q_h .* V_l   (bf16 out) — dtype-independent (ws only)
// ---------------------------------------------------------------------------
__global__ __launch_bounds__(256) void k_qv(
    const float* __restrict__ Ql, const float* __restrict__ Qh,
    const u16* __restrict__ Vl, const u16* __restrict__ Vh,
    u16* __restrict__ QV1, u16* __restrict__ QV2)
{
    int idx = blockIdx.x*256 + threadIdx.x;
    float4 q1 = ((const float4*)Ql)[idx];
    ushort4 vh = ((const ushort4*)Vh)[idx];
    u32 a0 = pack2(q1.x*bf2f(vh.x), q1.y*bf2f(vh.y));
    u32 a1 = pack2(q1.z*bf2f(vh.z), q1.w*bf2f(vh.w));
    ((uint2*)QV1)[idx] = make_uint2(a0,a1);
    float4 q2 = ((const float4*)Qh)[idx];
    ushort4 vl = ((const ushort4*)Vl)[idx];
    u32 b0 = pack2(q2.x*bf2f(vl.x), q2.y*bf2f(vl.y));
    u32 b1 = pack2(q2.z*bf2f(vl.z), q2.w*bf2f(vl.w));
    ((uint2*)QV2)[idx] = make_uint2(b0,b1);
}

// ---------------------------------------------------------------------------
// Flash-style attention — dtype-independent (ws only)
// which=0: Q_l,K_l,QV1 -> h_emb -> cat channels 256..511
// which=1: Q_h,K_h,QV2 -> l_emb -> cat channels 0..255
// ---------------------------------------------------------------------------
__global__ __launch_bounds__(256) void k_attn(
    const float* __restrict__ Ql, const float* __restrict__ Kl,
    const float* __restrict__ Qh, const float* __restrict__ Kh,
    const u16* __restrict__ QV1, const u16* __restrict__ QV2,
    u16* __restrict__ cat)
{
    int inst = blockIdx.y;
    int b = inst >> 1, which = inst & 1;
    const float* Q  = (which ? Qh  : Ql ) + (size_t)b*S_*C_;
    const float* K  = (which ? Kh  : Kl ) + (size_t)b*S_*C_;
    const u16*   QV = (which ? QV2 : QV1) + (size_t)b*S_*C_;
    u16* outp = cat + (size_t)b*S_*512 + (which ? 0 : 256);
    int sbase = blockIdx.x*32;
    int tid = threadIdx.x;

    __shared__ float sQ[32][258];
    __shared__ __align__(16) char ubuf[16384];    // union: sKc [32][66] f32  |  sPV [32][128] u32
    float (*sKc)[66] = (float(*)[66])ubuf;
    u32* sPV = (u32*)ubuf;
    __shared__ float sS[32][33];
    __shared__ float sM[32], sL[32], sAl[32];

    {
        int qs = tid>>3, qc = (tid&7)<<5;
        const float* src = Q + (size_t)(sbase+qs)*256 + qc;
        #pragma unroll
        for (int k = 0; k < 8; ++k){
            float4 v = *(const float4*)(src + 4*k);
            *(float2*)&sQ[qs][qc+4*k]   = make_float2(v.x,v.y);
            *(float2*)&sQ[qs][qc+4*k+2] = make_float2(v.z,v.w);
        }
    }
    if (tid < 32){ sM[tid] = -1e30f; sL[tid] = 0.f; }
    float accA[16] = {}; float accB[16] = {};
    int s0r = tid & 15, s1r = s0r + 16, cg = tid >> 4;
    int sp = (tid&15)*2, tp = (tid>>4)*2;
    int kt = tid>>3, kc = (tid&7)<<3;
    int pt = tid>>3, pcu = (tid&7)<<4;

    for (int t0 = 0; t0 < 1024; t0 += 32){
        float a00=0.f,a01=0.f,a10=0.f,a11=0.f;
        for (int ch = 0; ch < 4; ++ch){
            int c0 = ch*64;
            __syncthreads();
            {
                const float* ksrc = K + (size_t)(t0+kt)*256 + c0 + kc;
                float4 v0 = *(const float4*)ksrc;
                float4 v1 = *(const float4*)(ksrc+4);
                *(float2*)&sKc[kt][kc]   = make_float2(v0.x,v0.y);
                *(float2*)&sKc[kt][kc+2] = make_float2(v0.z,v0.w);
                *(float2*)&sKc[kt][kc+4] = make_float2(v1.x,v1.y);
                *(float2*)&sKc[kt][kc+6] = make_float2(v1.z,v1.w);
            }
            __syncthreads();
            const float* q0p = &sQ[sp][c0];
            const float* q1p = &sQ[sp+1][c0];
            const float* k0p = &sKc[tp][0];
            const float* k1p = &sKc[tp+1][0];
            #pragma unroll 8
            for (int c = 0; c < 64; c += 2){
                float2 q0 = *(const float2*)(q0p+c), q1 = *(const float2*)(q1p+c);
                float2 k0 = *(const float2*)(k0p+c), k1 = *(const float2*)(k1p+c);
                a00 += q0.x*k0.x; a01 += q0.x*k1.x; a10 += q1.x*k0.x; a11 += q1.x*k1.x;
                a00 += q0.y*k0.y; a01 += q0.y*k1.y; a10 += q1.y*k0.y; a11 += q1.y*k1.y;
            }
        }
        sS[sp][tp] = a00; sS[sp][tp+1] = a01; sS[sp+1][tp] = a10; sS[sp+1][tp+1] = a11;
        __syncthreads();
        {
            const u16* qsrc = QV + (size_t)(t0+pt)*256 + (pcu<<1);
            u32* dst = sPV + pt*128 + pcu;
            #pragma unroll
            for (int k = 0; k < 4; ++k){
                *(uint4*)(dst + 4*k) = *(const uint4*)(qsrc + 8*k);
            }
        }
        if (tid < 32){
            int s = tid;
            float m_old = sM[s];
            float mt = -1e30f;
            #pragma unroll
            for (int t = 0; t < 32; ++t) mt = fmaxf(mt, sS[s][t]);
            float m_new = fmaxf(m_old, mt);
            float al = expf(m_old - m_new);
            float ls = 0.f;
            #pragma unroll
            for (int t = 0; t < 32; ++t){
                float p = expf(sS[s][t] - m_new);
                sS[s][t] = p; ls += p;
            }
            sM[s] = m_new; sL[s] = sL[s]*al + ls; sAl[s] = al;
        }
        __syncthreads();
        float aA = sAl[s0r], aB = sAl[s1r];
        #pragma unroll
        for (int j = 0; j < 16; ++j){ accA[j] *= aA; accB[j] *= aB; }
        #pragma unroll 4
        for (int t = 0; t < 32; ++t){
            float pA = sS[s0r][t];
            float pB = sS[s1r][t];
            const uint4* pp = (const uint4*)(sPV + t*128 + (cg<<3));
            uint4 u0 = pp[0];
            uint4 u1 = pp[1];
            float f;
            f=lo16(u0.x); accA[0]+=pA*f;  accB[0]+=pB*f;
            f=hi16(u0.x); accA[1]+=pA*f;  accB[1]+=pB*f;
            f=lo16(u0.y); accA[2]+=pA*f;  accB[2]+=pB*f;
            f=hi16(u0.y); accA[3]+=pA*f;  accB[3]+=pB*f;
            f=lo16(u0.z); accA[4]+=pA*f;  accB[4]+=pB*f;
            f=hi16(u0.z); accA[5]+=pA*f;  accB[5]+=pB*f;
            f=lo16(u0.w); accA[6]+=pA*f;  accB[6]+=pB*f;
            f=hi16(u0.w); accA[7]+=pA*f;  accB[7]+=pB*f;
            f=lo16(u1.x); accA[8]+=pA*f;  accB[8]+=pB*f;
            f=hi16(u1.x); accA[9]+=pA*f;  accB[9]+=pB*f;
            f=lo16(u1.y); accA[10]+=pA*f; accB[10]+=pB*f;
            f=hi16(u1.y); accA[11]+=pA*f; accB[11]+=pB*f;
            f=lo16(u1.z); accA[12]+=pA*f; accB[12]+=pB*f;
            f=hi16(u1.z); accA[13]+=pA*f; accB[13]+=pB*f;
            f=lo16(u1.w); accA[14]+=pA*f; accB[14]+=pB*f;
            f=hi16(u1.w); accA[15]+=pA*f; accB[15]+=pB*f;
        }
    }
    float rA = 1.f/sL[s0r], rB = 1.f/sL[s1r];
    {
        u32 w[8];
        #pragma unroll
        for (int j = 0; j < 8; ++j) w[j] = pack2(accA[2*j]*rA, accA[2*j+1]*rA);
        u16* orow = outp + (size_t)(sbase+s0r)*512 + cg*16;
        *(uint4*)(orow)   = make_uint4(w[0],w[1],w[2],w[3]);
        *(uint4*)(orow+8) = make_uint4(w[4],w[5],w[6],w[7]);
        #pragma unroll
        for (int j = 0; j < 8; ++j) w[j] = pack2(accB[2*j]*rB, accB[2*j+1]*rB);
        u16* orow2 = outp + (size_t)(sbase+s1r)*512 + cg*16;
        *(uint4*)(orow2)   = make_uint4(w[0],w[1],w[2],w[3]);
        *(uint4*)(orow2+8) = make_uint4(w[4],w[5],w[6],w[7]);
    }
}

// ---------------------------------------------------------------------------
// 1x1 conv + bias + residual
// ---------------------------------------------------------------------------
template<bool BF16>
__global__ __launch_bounds__(256) void k_conv(
    const int* __restrict__ flag,
    const u16* __restrict__ cat, const void* __restrict__ cw,
    const void* __restrict__ cb, const void* __restrict__ x,
    void* __restrict__ out)
{
    if (*flag != (BF16 ? 1 : 0)) return;
    int b = blockIdx.z;
    int s0 = blockIdx.x*64, o0 = blockIdx.y*64;
    int tid = threadIdx.x;
    __shared__ float sW[32][68];   // [i][o]
    __shared__ float sC[32][68];   // [i][s]
    float acc[4][4] = {};
    int o4 = (tid>>4)<<2, s4 = (tid&15)<<2;
    const u16* catb = cat + (size_t)b*S_*512;
    for (int i0 = 0; i0 < 512; i0 += 32){
        __syncthreads();
        if constexpr (BF16){
            int w_o = tid>>2, w_i = (tid&3)<<3;
            uint4 v = *(const uint4*)((const u16*)cw + (size_t)(o0+w_o)*512 + i0 + w_i);
            sW[w_i+0][w_o]=lo16(v.x); sW[w_i+1][w_o]=hi16(v.x);
            sW[w_i+2][w_o]=lo16(v.y); sW[w_i+3][w_o]=hi16(v.y);
            sW[w_i+4][w_o]=lo16(v.z); sW[w_i+5][w_o]=hi16(v.z);
            sW[w_i+6][w_o]=lo16(v.w); sW[w_i+7][w_o]=hi16(v.w);
        } else {
            const float* cwf = (const float*)cw;
            int w_o = tid>>2, w_i = (tid&3)<<3;
            float4 a0 = *(const float4*)(cwf + (size_t)(o0+w_o)*512 + i0 + w_i);
            float4 a1 = *(const float4*)(cwf + (size_t)(o0+w_o)*512 + i0 + w_i + 4);
            sW[w_i+0][w_o]=a0.x; sW[w_i+1][w_o]=a0.y; sW[w_i+2][w_o]=a0.z; sW[w_i+3][w_o]=a0.w;
            sW[w_i+4][w_o]=a1.x; sW[w_i+5][w_o]=a1.y; sW[w_i+6][w_o]=a1.z; sW[w_i+7][w_o]=a1.w;
        }
        {
            int c_s = tid>>2, c_i = (tid&3)<<3;
            uint4 u = *(const uint4*)(catb + (size_t)(s0+c_s)*512 + i0 + c_i);
            sC[c_i+0][c_s]=lo16(u.x); sC[c_i+1][c_s]=hi16(u.x);
            sC[c_i+2][c_s]=lo16(u.y); sC[c_i+3][c_s]=hi16(u.y);
            sC[c_i+4][c_s]=lo16(u.z); sC[c_i+5][c_s]=hi16(u.z);
            sC[c_i+6][c_s]=lo16(u.w); sC[c_i+7][c_s]=hi16(u.w);
        }
        __syncthreads();
        #pragma unroll 8
        for (int i = 0; i < 32; ++i){
            float4 a  = *(const float4*)&sW[i][o4];
            float4 bb = *(const float4*)&sC[i][s4];
            acc[0][0]+=a.x*bb.x; acc[0][1]+=a.x*bb.y; acc[0][2]+=a.x*bb.z; acc[0][3]+=a.x*bb.w;
            acc[1][0]+=a.y*bb.x; acc[1][1]+=a.y*bb.y; acc[1][2]+=a.y*bb.z; acc[1][3]+=a.y*bb.w;
            acc[2][0]+=a.z*bb.x; acc[2][1]+=a.z*bb.y; acc[2][2]+=a.z*bb.z; acc[2][3]+=a.z*bb.w;
            acc[3][0]+=a.w*bb.x; acc[3][1]+=a.w*bb.y; acc[3][2]+=a.w*bb.z; acc[3][3]+=a.w*bb.w;
        }
    }
    #pragma unroll
    for (int i = 0; i < 4; ++i){
        float cbi = ldT<BF16>(cb, o0+o4+i);
        size_t base = (size_t)b*C_*S_ + (size_t)(o0+o4+i)*S_ + s0+s4;
        if constexpr (BF16){
            ushort4 xv = *(const ushort4*)((const u16*)x + base);
            u32 p0 = pack2(acc[i][0]+cbi+bf2f(xv.x), acc[i][1]+cbi+bf2f(xv.y));
            u32 p1 = pack2(acc[i][2]+cbi+bf2f(xv.z), acc[i][3]+cbi+bf2f(xv.w));
            *(uint2*)((u16*)out + base) = make_uint2(p0,p1);
        } else {
            float4 xv = *(const float4*)((const float*)x + base);
            float4 r = make_float4(acc[i][0]+cbi+xv.x, acc[i][1]+cbi+xv.y,
                                   acc[i][2]+cbi+xv.z, acc[i][3]+cbi+xv.w);
            *(float4*)((float*)out + base) = r;
        }
    }
}

// ---------------------------------------------------------------------------
extern "C" void kernel_launch(void* const* d_in, const int* in_sizes, int n_in,
                              void* d_out, int out_size, void* d_ws, size_t ws_size,
                              hipStream_t stream)
{
    const void* lidar = d_in[0];
    const void* hsi   = d_in[1];
    const void* x     = d_in[2];
    const void* Wq = d_in[3];  const void* bq = d_in[4];
    const void* Wk = d_in[5];  const void* bk = d_in[6];
    const void* Wv = d_in[7];  const void* bv = d_in[8];
    const void* cw = d_in[9];  const void* cb = d_in[10];
    const void* rw1 = d_in[11]; const void* rb1 = d_in[12];
    const void* rw2 = d_in[13]; const void* rb2 = d_in[14];
    char* ws = (char*)d_ws;

    // workspace map (bytes): Q/K fp32, QV/cat bf16, dtype flag at 192 MiB.
    float* Ql = (float*)(ws + 0);
    float* Kl = (float*)(ws + 33554432);
    float* Qh = (float*)(ws + 67108864);
    float* Kh = (float*)(ws + 100663296);
    u16* QV1  = (u16*)(ws + 134217728);
    u16* QV2  = (u16*)(ws + 150994944);
    u16* cat  = (u16*)(ws + 167772160);   // [32][1024][512] bf16
    int* flag = (int*)(ws + 201326592);
    u16* Vl   = cat;                      // temp alias (consumed before k_attn writes cat)
    u16* Vh   = cat + 8388608;

    k_detect<<<1, 256, 0, stream>>>((const u32*)lidar, flag);

    k_router<true ><<<32, 256, 0, stream>>>(flag, lidar, hsi, rw1, rb1, rw2, rb2, d_out);
    k_router<false><<<32, 256, 0, stream>>>(flag, lidar, hsi, rw1, rb1, rw2, rb2, d_out);

    k_qkv<true ><<<dim3(16,4,192), 256, 0, stream>>>(flag, lidar, hsi, Wq,bq,Wk,bk,Wv,bv, Ql,Kl,Qh,Kh, Vl,Vh);
    k_qkv<false><<<dim3(16,4,192), 256, 0, stream>>>(flag, lidar, hsi, Wq,bq,Wk,bk,Wv,bv, Ql,Kl,Qh,Kh, Vl,Vh);

    k_qv<<<8192, 256, 0, stream>>>(Ql, Qh, Vl, Vh, QV1, QV2);
    k_attn<<<dim3(32,64), 256, 0, stream>>>(Ql,Kl,Qh,Kh, QV1,QV2, cat);

    k_conv<true ><<<dim3(16,4,32), 256, 0, stream>>>(flag, cat, cw, cb, x, d_out);
    k_conv<false><<<dim3(16,4,32), 256, 0, stream>>>(flag, cat, cw, cb, x, d_out);
}

// Round 3
// 1883.361 us; speedup vs baseline: 1.7845x; 1.7845x over previous
//
#include <hip/hip_runtime.h>
#include <stdint.h>

typedef unsigned short u16;
typedef unsigned int u32;
typedef _Float16 f16;
typedef _Float16 f16x8 __attribute__((ext_vector_type(8)));
typedef _Float16 f16x4 __attribute__((ext_vector_type(4)));
typedef float f32x4 __attribute__((ext_vector_type(4)));

#define B_ 32
#define C_ 256
#define S_ 1024

__device__ __forceinline__ u16 f2bf(float f){
    u32 x = __float_as_uint(f);
    u32 r = (x + 0x7fffu + ((x>>16)&1u)) >> 16;
    return (u16)r;
}
__device__ __forceinline__ float lo16(u32 u){ return __uint_as_float(u<<16); }
__device__ __forceinline__ float hi16(u32 u){ return __uint_as_float(u & 0xffff0000u); }

// ---------------------------------------------------------------------------
// Router (fp32): g = mean concat(lidar,hsi); sigmoid(relu(g W1^T+b1) W2^T+b2)
// ---------------------------------------------------------------------------
__global__ __launch_bounds__(256) void k_router(
    const float* __restrict__ lidar, const float* __restrict__ hsi,
    const float* __restrict__ w1, const float* __restrict__ b1,
    const float* __restrict__ w2, const float* __restrict__ b2,
    float* __restrict__ out)   // path_prob at element offset 8388608
{
    int b = blockIdx.x;
    int tid = threadIdx.x;
    int wave = tid >> 6, lane = tid & 63;
    __shared__ float sg[512];
    __shared__ float sh[128];
    for (int row = wave; row < 512; row += 4){
        const float* src = (row < 256) ? lidar : hsi;
        size_t base = (size_t)b*C_*S_ + (size_t)(row & 255)*S_;
        float acc = 0.f;
        for (int k = lane; k < S_; k += 64) acc += src[base + k];
        #pragma unroll
        for (int off = 32; off > 0; off >>= 1) acc += __shfl_down(acc, off, 64);
        if (lane == 0) sg[row] = acc * (1.0f/1024.0f);
    }
    __syncthreads();
    if (tid < 128){
        float a = b1[tid];
        const float* w = w1 + (size_t)tid*512;
        for (int k = 0; k < 512; ++k) a += sg[k]*w[k];
        sh[tid] = fmaxf(a, 0.f);
    }
    __syncthreads();
    if (tid < 4){
        float a = b2[tid];
        const float* w = w2 + (size_t)tid*128;
        for (int k = 0; k < 128; ++k) a += sh[k]*w[k];
        out[(size_t)8388608 + b*4 + tid] = 1.f/(1.f+expf(-a));
    }
}

// ---------------------------------------------------------------------------
// QKV projections (fp32 VALU, fp32-accurate).  combo: 0=Q_l 1=K_l 2=V_l 3=Q_h 4=K_h 5=V_h
// Out[s][o] = sum_c W[o][c]*In[c][s] + bias[o]
// Q -> Qf[s][c] f16 (QK A-frag layout) + Qt[c][s] f16 (for QVT product)
// K -> Kf[t][c] f16 (QK B-frag layout)
// V -> Vt[c][s] f16
// ---------------------------------------------------------------------------
__global__ __launch_bounds__(256) void k_qkv(
    const float* __restrict__ lidar, const float* __restrict__ hsi,
    const float* __restrict__ Wq, const float* __restrict__ bq,
    const float* __restrict__ Wk, const float* __restrict__ bk,
    const float* __restrict__ Wv, const float* __restrict__ bv,
    f16* __restrict__ Qf_l, f16* __restrict__ Kf_l,
    f16* __restrict__ Qf_h, f16* __restrict__ Kf_h,
    f16* __restrict__ Qt_l, f16* __restrict__ Qt_h,
    f16* __restrict__ Vt_l, f16* __restrict__ Vt_h)
{
    int z = blockIdx.z;
    int combo = z >> 5, b = z & 31;
    int ww = combo % 3;
    const float* in = ((combo < 3) ? lidar : hsi) + (size_t)b*C_*S_;
    const float* W    = (ww==0) ? Wq : (ww==1) ? Wk : Wv;
    const float* bias = (ww==0) ? bq : (ww==1) ? bk : bv;
    int s0 = blockIdx.x*64, o0 = blockIdx.y*64;
    int tid = threadIdx.x;
    __shared__ float sW[32][68];   // [c][o]
    __shared__ float sI[32][68];   // [c][s]
    float acc[4][4] = {};
    int o4 = (tid>>4)<<2, s4 = (tid&15)<<2;
    for (int c0 = 0; c0 < 256; c0 += 32){
        __syncthreads();
        {
            int w_o = tid>>2, w_c = (tid&3)<<3;
            float4 a0 = *(const float4*)(W + (size_t)(o0+w_o)*256 + c0 + w_c);
            float4 a1 = *(const float4*)(W + (size_t)(o0+w_o)*256 + c0 + w_c + 4);
            sW[w_c+0][w_o]=a0.x; sW[w_c+1][w_o]=a0.y; sW[w_c+2][w_o]=a0.z; sW[w_c+3][w_o]=a0.w;
            sW[w_c+4][w_o]=a1.x; sW[w_c+5][w_o]=a1.y; sW[w_c+6][w_o]=a1.z; sW[w_c+7][w_o]=a1.w;
            int i_c = tid>>4, i_s = (tid&15)<<2;
            *(float4*)&sI[i_c][i_s]    = *(const float4*)(in + (size_t)(c0+i_c)*S_ + s0 + i_s);
            *(float4*)&sI[i_c+16][i_s] = *(const float4*)(in + (size_t)(c0+i_c+16)*S_ + s0 + i_s);
        }
        __syncthreads();
        #pragma unroll 8
        for (int c = 0; c < 32; ++c){
            float4 a  = *(const float4*)&sW[c][o4];
            float4 bb = *(const float4*)&sI[c][s4];
            acc[0][0]+=a.x*bb.x; acc[0][1]+=a.x*bb.y; acc[0][2]+=a.x*bb.z; acc[0][3]+=a.x*bb.w;
            acc[1][0]+=a.y*bb.x; acc[1][1]+=a.y*bb.y; acc[1][2]+=a.y*bb.z; acc[1][3]+=a.y*bb.w;
            acc[2][0]+=a.z*bb.x; acc[2][1]+=a.z*bb.y; acc[2][2]+=a.z*bb.z; acc[2][3]+=a.z*bb.w;
            acc[3][0]+=a.w*bb.x; acc[3][1]+=a.w*bb.y; acc[3][2]+=a.w*bb.z; acc[3][3]+=a.w*bb.w;
        }
    }
    float bi[4];
    #pragma unroll
    for (int i = 0; i < 4; ++i) bi[i] = bias[o0+o4+i];

    if (ww == 0){
        f16* F = ((combo==0)?Qf_l:Qf_h) + (size_t)b*S_*C_;
        f16* T = ((combo==0)?Qt_l:Qt_h) + (size_t)b*C_*S_;
        #pragma unroll
        for (int j = 0; j < 4; ++j){
            f16x4 v = { (f16)(acc[0][j]+bi[0]), (f16)(acc[1][j]+bi[1]),
                        (f16)(acc[2][j]+bi[2]), (f16)(acc[3][j]+bi[3]) };
            *(f16x4*)(F + (size_t)(s0+s4+j)*C_ + o0+o4) = v;
        }
        #pragma unroll
        for (int i = 0; i < 4; ++i){
            f16x4 v = { (f16)(acc[i][0]+bi[i]), (f16)(acc[i][1]+bi[i]),
                        (f16)(acc[i][2]+bi[i]), (f16)(acc[i][3]+bi[i]) };
            *(f16x4*)(T + (size_t)(o0+o4+i)*S_ + s0+s4) = v;
        }
    } else if (ww == 1){
        f16* F = ((combo==1)?Kf_l:Kf_h) + (size_t)b*S_*C_;
        #pragma unroll
        for (int j = 0; j < 4; ++j){
            f16x4 v = { (f16)(acc[0][j]+bi[0]), (f16)(acc[1][j]+bi[1]),
                        (f16)(acc[2][j]+bi[2]), (f16)(acc[3][j]+bi[3]) };
            *(f16x4*)(F + (size_t)(s0+s4+j)*C_ + o0+o4) = v;
        }
    } else {
        f16* T = ((combo==2)?Vt_l:Vt_h) + (size_t)b*C_*S_;
        #pragma unroll
        for (int i = 0; i < 4; ++i){
            f16x4 v = { (f16)(acc[i][0]+bi[i]), (f16)(acc[i][1]+bi[i]),
                        (f16)(acc[i][2]+bi[i]), (f16)(acc[i][3]+bi[i]) };
            *(f16x4*)(T + (size_t)(o0+o4+i)*S_ + s0+s4) = v;
        }
    }
}

// ---------------------------------------------------------------------------
// QVT1[c][s] = Qt_l*Vt_h ; QVT2[c][s] = Qt_h*Vt_l   (f16, elementwise)
// ---------------------------------------------------------------------------
__global__ __launch_bounds__(256) void k_qv(
    const f16* __restrict__ Qt_l, const f16* __restrict__ Qt_h,
    const f16* __restrict__ Vt_l, const f16* __restrict__ Vt_h,
    f16* __restrict__ QVT1, f16* __restrict__ QVT2)
{
    size_t idx = (size_t)(blockIdx.x*256 + threadIdx.x) * 8;
    f16x8 a = *(const f16x8*)(Qt_l+idx);
    f16x8 b = *(const f16x8*)(Vt_h+idx);
    f16x8 r;
    #pragma unroll
    for (int j = 0; j < 8; ++j) r[j] = (f16)((float)a[j]*(float)b[j]);
    *(f16x8*)(QVT1+idx) = r;
    f16x8 c = *(const f16x8*)(Qt_h+idx);
    f16x8 d = *(const f16x8*)(Vt_l+idx);
    f16x8 r2;
    #pragma unroll
    for (int j = 0; j < 8; ++j) r2[j] = (f16)((float)c[j]*(float)d[j]);
    *(f16x8*)(QVT2+idx) = r2;
}

// ---------------------------------------------------------------------------
// MFMA flash attention. Block: 64 q-rows of one (b,which). t-tiles BN=128.
// Scores: D[s][t] = sum_c Q[s][c]K[t][c]  (16x16x32 f16 MFMA)
//   wave tile 32s x 64t: sh=(w&1)*32, th=(w>>1)*64, 2 A-frags x 4 B-frags
// PV: D[s][c] = sum_t P[s][t] QVT[c][t]
//   wave: all 64 s x 64 c (wc=w*64), 4 A-frags x 4 B-frags
// Online softmax in-register + tiny LDS cross-wave combine.
// ---------------------------------------------------------------------------
__global__ __launch_bounds__(256) void k_attn(
    const f16* __restrict__ Qf_l, const f16* __restrict__ Kf_l,
    const f16* __restrict__ Qf_h, const f16* __restrict__ Kf_h,
    const f16* __restrict__ QVT1, const f16* __restrict__ QVT2,
    u16* __restrict__ cat)
{
    int inst = blockIdx.y;
    int b = inst >> 1, which = inst & 1;
    const f16* Qf  = (which ? Qf_h : Qf_l) + (size_t)b*S_*C_;
    const f16* Kf  = (which ? Kf_h : Kf_l) + (size_t)b*S_*C_;
    const f16* QVT = (which ? QVT2 : QVT1) + (size_t)b*C_*S_;
    u16* outp = cat + (size_t)b*S_*512 + (which ? 0 : 256);
    int s0 = blockIdx.x*64;
    int tid = threadIdx.x;
    int w = tid>>6, lane = tid&63, quad = lane>>4, l15 = lane&15;
    int sh = (w&1)*32, th = (w>>1)*64, wc = w*64;
    int whalf = w>>1;

    // strides chosen so row-stride ≡ 4 words (mod 32): only 2-way conflicts (free)
    __shared__ __align__(16) f16 sQc[64*72];     //  9216 B, Q c-chunk [64][64]+pad8
    __shared__ __align__(16) f16 uKV[10240];     // 20480 B union: sK[128][72] | sQVT[256][40]
    __shared__ __align__(16) f16 sP[64*136];     // 17408 B, P [64][128]+pad8
    __shared__ float sRed[2][64][2];
    __shared__ float sState[64][2];              // running m, l
    __shared__ float sAlpha[64];

    if (tid < 64){ sState[tid][0] = -1e30f; sState[tid][1] = 0.f; }

    f32x4 pacc[4][4];
    #pragma unroll
    for (int i = 0; i < 4; ++i)
        #pragma unroll
        for (int j = 0; j < 4; ++j) pacc[i][j] = (f32x4){0.f,0.f,0.f,0.f};

    for (int tt = 0; tt < 8; ++tt){
        int t0 = tt*128;
        f32x4 sacc[2][4];
        #pragma unroll
        for (int i = 0; i < 2; ++i)
            #pragma unroll
            for (int j = 0; j < 4; ++j) sacc[i][j] = (f32x4){0.f,0.f,0.f,0.f};

        // ---- scores ----
        for (int c0 = 0; c0 < 256; c0 += 64){
            __syncthreads();   // prior readers of sQc/uKV done
            #pragma unroll
            for (int p = 0; p < 2; ++p){
                int idx = p*256 + tid; int row = idx>>3, c8 = (idx&7)*8;
                *(f16x8*)&sQc[row*72 + c8] = *(const f16x8*)(Qf + (size_t)(s0+row)*C_ + c0 + c8);
            }
            #pragma unroll
            for (int p = 0; p < 4; ++p){
                int idx = p*256 + tid; int row = idx>>3, c8 = (idx&7)*8;
                *(f16x8*)&uKV[row*72 + c8] = *(const f16x8*)(Kf + (size_t)(t0+row)*C_ + c0 + c8);
            }
            __syncthreads();
            #pragma unroll
            for (int sub = 0; sub < 2; ++sub){
                f16x8 qa0 = *(const f16x8*)&sQc[(sh+l15)*72    + sub*32 + quad*8];
                f16x8 qa1 = *(const f16x8*)&sQc[(sh+16+l15)*72 + sub*32 + quad*8];
                #pragma unroll
                for (int bt = 0; bt < 4; ++bt){
                    f16x8 kb = *(const f16x8*)&uKV[(th+16*bt+l15)*72 + sub*32 + quad*8];
                    sacc[0][bt] = __builtin_amdgcn_mfma_f32_16x16x32_f16(qa0, kb, sacc[0][bt], 0,0,0);
                    sacc[1][bt] = __builtin_amdgcn_mfma_f32_16x16x32_f16(qa1, kb, sacc[1][bt], 0,0,0);
                }
            }
        }

        // ---- online softmax ----
        // D layout: col=l15 (t), row=quad*4+reg (s within 16-tile)
        float rmax[2][4];
        #pragma unroll
        for (int a = 0; a < 2; ++a)
            #pragma unroll
            for (int r = 0; r < 4; ++r){
                float m = fmaxf(fmaxf(sacc[a][0][r], sacc[a][1][r]),
                                fmaxf(sacc[a][2][r], sacc[a][3][r]));
                #pragma unroll
                for (int off = 1; off < 16; off <<= 1) m = fmaxf(m, __shfl_xor(m, off, 64));
                rmax[a][r] = m;
            }
        if (l15 == 0){
            #pragma unroll
            for (int a = 0; a < 2; ++a)
                #pragma unroll
                for (int r = 0; r < 4; ++r)
                    sRed[whalf][sh+16*a+quad*4+r][0] = rmax[a][r];
        }
        __syncthreads();
        float psum[2][4];
        #pragma unroll
        for (int a = 0; a < 2; ++a)
            #pragma unroll
            for (int r = 0; r < 4; ++r){
                int s = sh + 16*a + quad*4 + r;
                float mn = fmaxf(sState[s][0], fmaxf(sRed[0][s][0], sRed[1][s][0]));
                float acc = 0.f;
                #pragma unroll
                for (int bt = 0; bt < 4; ++bt){
                    float p = __expf(sacc[a][bt][r] - mn);
                    sP[s*136 + th + 16*bt + l15] = (f16)p;
                    acc += p;
                }
                #pragma unroll
                for (int off = 1; off < 16; off <<= 1) acc += __shfl_xor(acc, off, 64);
                psum[a][r] = acc;
            }
        if (l15 == 0){
            #pragma unroll
            for (int a = 0; a < 2; ++a)
                #pragma unroll
                for (int r = 0; r < 4; ++r)
                    sRed[whalf][sh+16*a+quad*4+r][1] = psum[a][r];
        }
        __syncthreads();
        if (tid < 64){
            int s = tid;
            float mo = sState[s][0];
            float mn = fmaxf(mo, fmaxf(sRed[0][s][0], sRed[1][s][0]));
            float al = __expf(mo - mn);
            sState[s][0] = mn;
            sState[s][1] = sState[s][1]*al + sRed[0][s][1] + sRed[1][s][1];
            sAlpha[s] = al;
        }
        __syncthreads();

        // rescale accumulators by alpha (per row)
        #pragma unroll
        for (int a2 = 0; a2 < 4; ++a2){
            float al[4];
            #pragma unroll
            for (int r = 0; r < 4; ++r) al[r] = sAlpha[16*a2 + quad*4 + r];
            #pragma unroll
            for (int bt = 0; bt < 4; ++bt)
                #pragma unroll
                for (int r = 0; r < 4; ++r) pacc[a2][bt][r] *= al[r];
        }

        // ---- PV ----
        for (int tsub = 0; tsub < 4; ++tsub){
            __syncthreads();   // uKV readers done
            #pragma unroll
            for (int p = 0; p < 4; ++p){
                int idx = p*256 + tid; int row = idx>>2, t8 = (idx&3)*8;
                *(f16x8*)&uKV[row*40 + t8] =
                    *(const f16x8*)(QVT + (size_t)row*S_ + t0 + tsub*32 + t8);
            }
            __syncthreads();
            f16x8 pa[4];
            #pragma unroll
            for (int a2 = 0; a2 < 4; ++a2)
                pa[a2] = *(const f16x8*)&sP[(16*a2+l15)*136 + tsub*32 + quad*8];
            #pragma unroll
            for (int bt = 0; bt < 4; ++bt){
                f16x8 qb = *(const f16x8*)&uKV[(wc+16*bt+l15)*40 + quad*8];
                #pragma unroll
                for (int a2 = 0; a2 < 4; ++a2)
                    pacc[a2][bt] = __builtin_amdgcn_mfma_f32_16x16x32_f16(pa[a2], qb, pacc[a2][bt], 0,0,0);
            }
        }
    }

    // ---- epilogue: scale by 1/l, write cat (bf16) ----
    #pragma unroll
    for (int a2 = 0; a2 < 4; ++a2)
        #pragma unroll
        for (int r = 0; r < 4; ++r){
            int s = 16*a2 + quad*4 + r;
            float rl = 1.f / sState[s][1];
            #pragma unroll
            for (int bt = 0; bt < 4; ++bt){
                int c = wc + 16*bt + l15;
                outp[(size_t)(s0+s)*512 + c] = f2bf(pacc[a2][bt][r] * rl);
            }
        }
}

// ---------------------------------------------------------------------------
// 1x1 conv + bias + residual (fp32 VALU): out[b][o][s] = sum_i cw[o][i]*cat[s][i] + cb[o] + x
// ---------------------------------------------------------------------------
__global__ __launch_bounds__(256) void k_conv(
    const u16* __restrict__ cat, const float* __restrict__ cw,
    const float* __restrict__ cb, const float* __restrict__ x,
    float* __restrict__ out)
{
    int b = blockIdx.z;
    int s0 = blockIdx.x*64, o0 = blockIdx.y*64;
    int tid = threadIdx.x;
    __shared__ float sW[32][68];   // [i][o]
    __shared__ float sC[32][68];   // [i][s]
    float acc[4][4] = {};
    int o4 = (tid>>4)<<2, s4 = (tid&15)<<2;
    const u16* catb = cat + (size_t)b*S_*512;
    for (int i0 = 0; i0 < 512; i0 += 32){
        __syncthreads();
        {
            int w_o = tid>>2, w_i = (tid&3)<<3;
            float4 a0 = *(const float4*)(cw + (size_t)(o0+w_o)*512 + i0 + w_i);
            float4 a1 = *(const float4*)(cw + (size_t)(o0+w_o)*512 + i0 + w_i + 4);
            sW[w_i+0][w_o]=a0.x; sW[w_i+1][w_o]=a0.y; sW[w_i+2][w_o]=a0.z; sW[w_i+3][w_o]=a0.w;
            sW[w_i+4][w_o]=a1.x; sW[w_i+5][w_o]=a1.y; sW[w_i+6][w_o]=a1.z; sW[w_i+7][w_o]=a1.w;
        }
        {
            int c_s = tid>>2, c_i = (tid&3)<<3;
            uint4 u = *(const uint4*)(catb + (size_t)(s0+c_s)*512 + i0 + c_i);
            sC[c_i+0][c_s]=lo16(u.x); sC[c_i+1][c_s]=hi16(u.x);
            sC[c_i+2][c_s]=lo16(u.y); sC[c_i+3][c_s]=hi16(u.y);
            sC[c_i+4][c_s]=lo16(u.z); sC[c_i+5][c_s]=hi16(u.z);
            sC[c_i+6][c_s]=lo16(u.w); sC[c_i+7][c_s]=hi16(u.w);
        }
        __syncthreads();
        #pragma unroll 8
        for (int i = 0; i < 32; ++i){
            float4 a  = *(const float4*)&sW[i][o4];
            float4 bb = *(const float4*)&sC[i][s4];
            acc[0][0]+=a.x*bb.x; acc[0][1]+=a.x*bb.y; acc[0][2]+=a.x*bb.z; acc[0][3]+=a.x*bb.w;
            acc[1][0]+=a.y*bb.x; acc[1][1]+=a.y*bb.y; acc[1][2]+=a.y*bb.z; acc[1][3]+=a.y*bb.w;
            acc[2][0]+=a.z*bb.x; acc[2][1]+=a.z*bb.y; acc[2][2]+=a.z*bb.z; acc[2][3]+=a.z*bb.w;
            acc[3][0]+=a.w*bb.x; acc[3][1]+=a.w*bb.y; acc[3][2]+=a.w*bb.z; acc[3][3]+=a.w*bb.w;
        }
    }
    #pragma unroll
    for (int i = 0; i < 4; ++i){
        float cbi = cb[o0+o4+i];
        size_t base = (size_t)b*C_*S_ + (size_t)(o0+o4+i)*S_ + s0+s4;
        float4 xv = *(const float4*)(x + base);
        float4 r = make_float4(acc[i][0]+cbi+xv.x, acc[i][1]+cbi+xv.y,
                               acc[i][2]+cbi+xv.z, acc[i][3]+cbi+xv.w);
        *(float4*)(out + base) = r;
    }
}

// ---------------------------------------------------------------------------
extern "C" void kernel_launch(void* const* d_in, const int* in_sizes, int n_in,
                              void* d_out, int out_size, void* d_ws, size_t ws_size,
                              hipStream_t stream)
{
    const float* lidar = (const float*)d_in[0];
    const float* hsi   = (const float*)d_in[1];
    const float* x     = (const float*)d_in[2];
    const float* Wq = (const float*)d_in[3];  const float* bq = (const float*)d_in[4];
    const float* Wk = (const float*)d_in[5];  const float* bk = (const float*)d_in[6];
    const float* Wv = (const float*)d_in[7];  const float* bv = (const float*)d_in[8];
    const float* cw = (const float*)d_in[9];  const float* cb = (const float*)d_in[10];
    const float* rw1 = (const float*)d_in[11]; const float* rb1 = (const float*)d_in[12];
    const float* rw2 = (const float*)d_in[13]; const float* rb2 = (const float*)d_in[14];
    char* ws = (char*)d_ws;
    const size_t M = 1u<<20;

    // workspace map: 11 tensors of 16 MiB (f16 32x1024x256) + 32 MiB cat = 192 MiB
    f16* Qf_l = (f16*)(ws +   0*M);
    f16* Kf_l = (f16*)(ws +  16*M);
    f16* Qf_h = (f16*)(ws +  32*M);
    f16* Kf_h = (f16*)(ws +  48*M);
    f16* Qt_l = (f16*)(ws +  64*M);
    f16* Qt_h = (f16*)(ws +  80*M);
    f16* Vt_l = (f16*)(ws +  96*M);
    f16* Vt_h = (f16*)(ws + 112*M);
    f16* QVT1 = (f16*)(ws + 128*M);
    f16* QVT2 = (f16*)(ws + 144*M);
    u16* cat  = (u16*)(ws + 160*M);   // [32][1024][512] bf16

    k_router<<<32, 256, 0, stream>>>(lidar, hsi, rw1, rb1, rw2, rb2, (float*)d_out);
    k_qkv<<<dim3(16,4,192), 256, 0, stream>>>(lidar, hsi, Wq,bq,Wk,bk,Wv,bv,
                                              Qf_l,Kf_l,Qf_h,Kf_h, Qt_l,Qt_h,Vt_l,Vt_h);
    k_qv<<<4096, 256, 0, stream>>>(Qt_l, Qt_h, Vt_l, Vt_h, QVT1, QVT2);
    k_attn<<<dim3(16,64), 256, 0, stream>>>(Qf_l,Kf_l,Qf_h,Kf_h, QVT1,QVT2, cat);
    k_conv<<<dim3(16,4,32), 256, 0, stream>>>(cat, cw, cb, x, (float*)d_out);
}

// Round 4
// 512.986 us; speedup vs baseline: 6.5517x; 3.6714x over previous
//
#include <hip/hip_runtime.h>
#include <stdint.h>

typedef unsigned short u16;
typedef unsigned int u32;
typedef _Float16 f16;
typedef _Float16 f16x8 __attribute__((ext_vector_type(8)));
typedef _Float16 f16x4 __attribute__((ext_vector_type(4)));
typedef float f32x4 __attribute__((ext_vector_type(4)));

#define B_ 32
#define C_ 256
#define S_ 1024

// ---------------------------------------------------------------------------
// Pool: g[b][row] = mean over s of concat(lidar,hsi)[b][row][:]
// one wave per row -> 4096 blocks
// ---------------------------------------------------------------------------
__global__ __launch_bounds__(256) void k_pool(
    const float* __restrict__ lidar, const float* __restrict__ hsi,
    float* __restrict__ g)
{
    int r = blockIdx.x*4 + (threadIdx.x>>6);
    int lane = threadIdx.x & 63;
    int b = r >> 9, row = r & 511;
    const float* src = ((row < 256) ? lidar : hsi) + (size_t)b*C_*S_ + (size_t)(row & 255)*S_;
    const float4* p = (const float4*)src;
    float acc = 0.f;
    #pragma unroll
    for (int j = 0; j < 4; ++j){
        float4 v = p[j*64 + lane];
        acc += v.x + v.y + v.z + v.w;
    }
    #pragma unroll
    for (int off = 32; off > 0; off >>= 1) acc += __shfl_down(acc, off, 64);
    if (lane == 0) g[r] = acc * (1.0f/1024.0f);
}

// ---------------------------------------------------------------------------
// Router MLP: path_prob = sigmoid(relu(g W1^T + b1) W2^T + b2); one block per b
// ---------------------------------------------------------------------------
__global__ __launch_bounds__(256) void k_mlp(
    const float* __restrict__ g,
    const float* __restrict__ w1, const float* __restrict__ b1,
    const float* __restrict__ w2, const float* __restrict__ b2,
    float* __restrict__ out)
{
    int b = blockIdx.x, tid = threadIdx.x;
    __shared__ float sg[512];
    __shared__ float sh[128];
    sg[tid] = g[b*512 + tid];
    sg[tid+256] = g[b*512 + 256 + tid];
    __syncthreads();
    if (tid < 128){
        float a = b1[tid];
        const float* w = w1 + (size_t)tid*512;
        #pragma unroll 4
        for (int k = 0; k < 512; k += 4){
            float4 wv = *(const float4*)(w + k);
            a += sg[k]*wv.x + sg[k+1]*wv.y + sg[k+2]*wv.z + sg[k+3]*wv.w;
        }
        sh[tid] = fmaxf(a, 0.f);
    }
    __syncthreads();
    if (tid < 4){
        float a = b2[tid];
        const float* w = w2 + (size_t)tid*128;
        for (int k = 0; k < 128; ++k) a += sh[k]*w[k];
        out[(size_t)8388608 + b*4 + tid] = 1.f/(1.f+expf(-a));
    }
}

// ---------------------------------------------------------------------------
// Weight convert fp32 -> f16 (Wq, Wk, Wv 256x256 ; cw 256x512), layouts kept
// ---------------------------------------------------------------------------
__global__ __launch_bounds__(256) void k_cvtw(
    const float* __restrict__ Wq, const float* __restrict__ Wk,
    const float* __restrict__ Wv, const float* __restrict__ cw,
    f16* __restrict__ Wqf, f16* __restrict__ Wkf,
    f16* __restrict__ Wvf, f16* __restrict__ cwf)
{
    int i = (blockIdx.x*256 + threadIdx.x) * 4;
    const float* src; f16* dst; int off;
    if (i < 65536){ src = Wq; dst = Wqf; off = i; }
    else if (i < 131072){ src = Wk; dst = Wkf; off = i - 65536; }
    else if (i < 196608){ src = Wv; dst = Wvf; off = i - 131072; }
    else { src = cw; dst = cwf; off = i - 196608; }
    float4 v = *(const float4*)(src + off);
    f16x4 r = { (f16)v.x, (f16)v.y, (f16)v.z, (f16)v.w };
    *(f16x4*)(dst + off) = r;
}

// ---------------------------------------------------------------------------
// Input convert+transpose: fp32 [c][s] -> f16 [s][c]  (in-register 4x4)
// ---------------------------------------------------------------------------
__global__ __launch_bounds__(256) void k_cvt(
    const float* __restrict__ lidar, const float* __restrict__ hsi,
    f16* __restrict__ lidT, f16* __restrict__ hsiT)
{
    int z = blockIdx.z, which = z >> 5, b = z & 31;
    const float* src = (which ? hsi : lidar) + (size_t)b*C_*S_;
    f16* dst = (which ? hsiT : lidT) + (size_t)b*S_*C_;
    int tid = threadIdx.x;
    int c4 = blockIdx.y*64 + (tid&15)*4;
    int s4 = blockIdx.x*64 + (tid>>4)*4;
    float4 m[4];
    #pragma unroll
    for (int r = 0; r < 4; ++r) m[r] = *(const float4*)(src + (size_t)(c4+r)*S_ + s4);
    f16x4 t0 = { (f16)m[0].x, (f16)m[1].x, (f16)m[2].x, (f16)m[3].x };
    f16x4 t1 = { (f16)m[0].y, (f16)m[1].y, (f16)m[2].y, (f16)m[3].y };
    f16x4 t2 = { (f16)m[0].z, (f16)m[1].z, (f16)m[2].z, (f16)m[3].z };
    f16x4 t3 = { (f16)m[0].w, (f16)m[1].w, (f16)m[2].w, (f16)m[3].w };
    *(f16x4*)(dst + (size_t)(s4+0)*C_ + c4) = t0;
    *(f16x4*)(dst + (size_t)(s4+1)*C_ + c4) = t1;
    *(f16x4*)(dst + (size_t)(s4+2)*C_ + c4) = t2;
    *(f16x4*)(dst + (size_t)(s4+3)*C_ + c4) = t3;
}

// ---------------------------------------------------------------------------
// QKV projections, f16 MFMA.  combo: 0=Q_l 1=K_l 2=V_l 3=Q_h 4=K_h 5=V_h
// D[s][o] = sum_c In_t[s][c] * W[o][c] + bias[o]   (16x16x32, A rows=s, B rows=o)
// Q -> Qf[s][o] (direct) + Qt[o][s] (LDS transpose); K -> Kf[s][o]; V -> Vt[o][s]
// ---------------------------------------------------------------------------
__global__ __launch_bounds__(256) void k_qkv(
    const f16* __restrict__ lidT, const f16* __restrict__ hsiT,
    const f16* __restrict__ Wqf, const f16* __restrict__ Wkf, const f16* __restrict__ Wvf,
    const float* __restrict__ bq, const float* __restrict__ bk, const float* __restrict__ bv,
    f16* __restrict__ Qf_l, f16* __restrict__ Kf_l,
    f16* __restrict__ Qf_h, f16* __restrict__ Kf_h,
    f16* __restrict__ Qt_l, f16* __restrict__ Qt_h,
    f16* __restrict__ Vt_l, f16* __restrict__ Vt_h)
{
    int z = blockIdx.z, combo = z >> 5, b = z & 31, ww = combo % 3;
    const f16* In = ((combo < 3) ? lidT : hsiT) + (size_t)b*S_*C_;
    const f16* Wf = (ww==0) ? Wqf : (ww==1) ? Wkf : Wvf;
    const float* bias = (ww==0) ? bq : (ww==1) ? bk : bv;
    int s0 = blockIdx.x*64, o0 = blockIdx.y*64;
    int tid = threadIdx.x, w = tid>>6, lane = tid&63, quad = lane>>4, l15 = lane&15;

    __shared__ __align__(16) f16 sA[64*72];   // In tile [s][c-chunk]
    __shared__ __align__(16) f16 sB[64*72];   // W  tile [o][c-chunk]

    f32x4 D[4];
    #pragma unroll
    for (int i = 0; i < 4; ++i) D[i] = (f32x4){0.f,0.f,0.f,0.f};

    int row = tid>>2, c16 = (tid&3)*16;
    for (int c0 = 0; c0 < 256; c0 += 64){
        __syncthreads();
        *(f16x8*)&sA[row*72 + c16]     = *(const f16x8*)(In + (size_t)(s0+row)*C_ + c0 + c16);
        *(f16x8*)&sA[row*72 + c16 + 8] = *(const f16x8*)(In + (size_t)(s0+row)*C_ + c0 + c16 + 8);
        *(f16x8*)&sB[row*72 + c16]     = *(const f16x8*)(Wf + (size_t)(o0+row)*C_ + c0 + c16);
        *(f16x8*)&sB[row*72 + c16 + 8] = *(const f16x8*)(Wf + (size_t)(o0+row)*C_ + c0 + c16 + 8);
        __syncthreads();
        #pragma unroll
        for (int sub = 0; sub < 2; ++sub){
            f16x8 a = *(const f16x8*)&sA[(w*16+l15)*72 + sub*32 + quad*8];
            #pragma unroll
            for (int bt = 0; bt < 4; ++bt){
                f16x8 bb = *(const f16x8*)&sB[(bt*16+l15)*72 + sub*32 + quad*8];
                D[bt] = __builtin_amdgcn_mfma_f32_16x16x32_f16(a, bb, D[bt], 0,0,0);
            }
        }
    }
    float bi[4];
    #pragma unroll
    for (int bt = 0; bt < 4; ++bt) bi[bt] = bias[o0 + bt*16 + l15];

    // s_loc = w*16 + quad*4 + r ; o_loc = bt*16 + l15
    if (ww == 0){
        f16* F = ((combo==0) ? Qf_l : Qf_h) + (size_t)b*S_*C_;
        #pragma unroll
        for (int bt = 0; bt < 4; ++bt)
            #pragma unroll
            for (int r = 0; r < 4; ++r)
                F[(size_t)(s0 + w*16 + quad*4 + r)*C_ + o0 + bt*16 + l15] = (f16)(D[bt][r] + bi[bt]);
    } else if (ww == 1){
        f16* F = ((combo==1) ? Kf_l : Kf_h) + (size_t)b*S_*C_;
        #pragma unroll
        for (int bt = 0; bt < 4; ++bt)
            #pragma unroll
            for (int r = 0; r < 4; ++r)
                F[(size_t)(s0 + w*16 + quad*4 + r)*C_ + o0 + bt*16 + l15] = (f16)(D[bt][r] + bi[bt]);
    }
    if (ww != 1){
        __syncthreads();   // done with sA MFMA reads
        #pragma unroll
        for (int bt = 0; bt < 4; ++bt)
            #pragma unroll
            for (int r = 0; r < 4; ++r)
                sA[(bt*16+l15)*72 + w*16 + quad*4 + r] = (f16)(D[bt][r] + bi[bt]);
        __syncthreads();
        f16* T = (combo==0) ? Qt_l : (combo==3) ? Qt_h : (combo==2) ? Vt_l : Vt_h;
        T += (size_t)b*C_*S_;
        int o_r = tid>>2, s16b = (tid&3)*16;
        *(f16x8*)(T + (size_t)(o0+o_r)*S_ + s0 + s16b)     = *(const f16x8*)&sA[o_r*72 + s16b];
        *(f16x8*)(T + (size_t)(o0+o_r)*S_ + s0 + s16b + 8) = *(const f16x8*)&sA[o_r*72 + s16b + 8];
    }
}

// ---------------------------------------------------------------------------
// QVT1[c][s] = Qt_l*Vt_h ; QVT2[c][s] = Qt_h*Vt_l   (f16 elementwise)
// ---------------------------------------------------------------------------
__global__ __launch_bounds__(256) void k_qv(
    const f16* __restrict__ Qt_l, const f16* __restrict__ Qt_h,
    const f16* __restrict__ Vt_l, const f16* __restrict__ Vt_h,
    f16* __restrict__ QVT1, f16* __restrict__ QVT2)
{
    size_t idx = (size_t)(blockIdx.x*256 + threadIdx.x) * 8;
    f16x8 a = *(const f16x8*)(Qt_l+idx);
    f16x8 b = *(const f16x8*)(Vt_h+idx);
    *(f16x8*)(QVT1+idx) = a*b;
    f16x8 c = *(const f16x8*)(Qt_h+idx);
    f16x8 d = *(const f16x8*)(Vt_l+idx);
    *(f16x8*)(QVT2+idx) = c*d;
}

// ---------------------------------------------------------------------------
// MFMA flash attention (as round 3; cat now f16)
// ---------------------------------------------------------------------------
__global__ __launch_bounds__(256) void k_attn(
    const f16* __restrict__ Qf_l, const f16* __restrict__ Kf_l,
    const f16* __restrict__ Qf_h, const f16* __restrict__ Kf_h,
    const f16* __restrict__ QVT1, const f16* __restrict__ QVT2,
    f16* __restrict__ cat)
{
    int inst = blockIdx.y;
    int b = inst >> 1, which = inst & 1;
    const f16* Qf  = (which ? Qf_h : Qf_l) + (size_t)b*S_*C_;
    const f16* Kf  = (which ? Kf_h : Kf_l) + (size_t)b*S_*C_;
    const f16* QVT = (which ? QVT2 : QVT1) + (size_t)b*C_*S_;
    f16* outp = cat + (size_t)b*S_*512 + (which ? 0 : 256);
    int s0 = blockIdx.x*64;
    int tid = threadIdx.x;
    int w = tid>>6, lane = tid&63, quad = lane>>4, l15 = lane&15;
    int sh = (w&1)*32, th = (w>>1)*64, wc = w*64;
    int whalf = w>>1;

    __shared__ __align__(16) f16 sQc[64*72];
    __shared__ __align__(16) f16 uKV[10240];     // union: sK[128][72] | sQVT[256][40]
    __shared__ __align__(16) f16 sP[64*136];
    __shared__ float sRed[2][64][2];
    __shared__ float sState[64][2];
    __shared__ float sAlpha[64];

    if (tid < 64){ sState[tid][0] = -1e30f; sState[tid][1] = 0.f; }

    f32x4 pacc[4][4];
    #pragma unroll
    for (int i = 0; i < 4; ++i)
        #pragma unroll
        for (int j = 0; j < 4; ++j) pacc[i][j] = (f32x4){0.f,0.f,0.f,0.f};

    for (int tt = 0; tt < 8; ++tt){
        int t0 = tt*128;
        f32x4 sacc[2][4];
        #pragma unroll
        for (int i = 0; i < 2; ++i)
            #pragma unroll
            for (int j = 0; j < 4; ++j) sacc[i][j] = (f32x4){0.f,0.f,0.f,0.f};

        for (int c0 = 0; c0 < 256; c0 += 64){
            __syncthreads();
            #pragma unroll
            for (int p = 0; p < 2; ++p){
                int idx = p*256 + tid; int row = idx>>3, c8 = (idx&7)*8;
                *(f16x8*)&sQc[row*72 + c8] = *(const f16x8*)(Qf + (size_t)(s0+row)*C_ + c0 + c8);
            }
            #pragma unroll
            for (int p = 0; p < 4; ++p){
                int idx = p*256 + tid; int row = idx>>3, c8 = (idx&7)*8;
                *(f16x8*)&uKV[row*72 + c8] = *(const f16x8*)(Kf + (size_t)(t0+row)*C_ + c0 + c8);
            }
            __syncthreads();
            #pragma unroll
            for (int sub = 0; sub < 2; ++sub){
                f16x8 qa0 = *(const f16x8*)&sQc[(sh+l15)*72    + sub*32 + quad*8];
                f16x8 qa1 = *(const f16x8*)&sQc[(sh+16+l15)*72 + sub*32 + quad*8];
                #pragma unroll
                for (int bt = 0; bt < 4; ++bt){
                    f16x8 kb = *(const f16x8*)&uKV[(th+16*bt+l15)*72 + sub*32 + quad*8];
                    sacc[0][bt] = __builtin_amdgcn_mfma_f32_16x16x32_f16(qa0, kb, sacc[0][bt], 0,0,0);
                    sacc[1][bt] = __builtin_amdgcn_mfma_f32_16x16x32_f16(qa1, kb, sacc[1][bt], 0,0,0);
                }
            }
        }

        float rmax[2][4];
        #pragma unroll
        for (int a = 0; a < 2; ++a)
            #pragma unroll
            for (int r = 0; r < 4; ++r){
                float m = fmaxf(fmaxf(sacc[a][0][r], sacc[a][1][r]),
                                fmaxf(sacc[a][2][r], sacc[a][3][r]));
                #pragma unroll
                for (int off = 1; off < 16; off <<= 1) m = fmaxf(m, __shfl_xor(m, off, 64));
                rmax[a][r] = m;
            }
        if (l15 == 0){
            #pragma unroll
            for (int a = 0; a < 2; ++a)
                #pragma unroll
                for (int r = 0; r < 4; ++r)
                    sRed[whalf][sh+16*a+quad*4+r][0] = rmax[a][r];
        }
        __syncthreads();
        float psum[2][4];
        #pragma unroll
        for (int a = 0; a < 2; ++a)
            #pragma unroll
            for (int r = 0; r < 4; ++r){
                int s = sh + 16*a + quad*4 + r;
                float mn = fmaxf(sState[s][0], fmaxf(sRed[0][s][0], sRed[1][s][0]));
                float acc = 0.f;
                #pragma unroll
                for (int bt = 0; bt < 4; ++bt){
                    float p = __expf(sacc[a][bt][r] - mn);
                    sP[s*136 + th + 16*bt + l15] = (f16)p;
                    acc += p;
                }
                #pragma unroll
                for (int off = 1; off < 16; off <<= 1) acc += __shfl_xor(acc, off, 64);
                psum[a][r] = acc;
            }
        if (l15 == 0){
            #pragma unroll
            for (int a = 0; a < 2; ++a)
                #pragma unroll
                for (int r = 0; r < 4; ++r)
                    sRed[whalf][sh+16*a+quad*4+r][1] = psum[a][r];
        }
        __syncthreads();
        if (tid < 64){
            int s = tid;
            float mo = sState[s][0];
            float mn = fmaxf(mo, fmaxf(sRed[0][s][0], sRed[1][s][0]));
            float al = __expf(mo - mn);
            sState[s][0] = mn;
            sState[s][1] = sState[s][1]*al + sRed[0][s][1] + sRed[1][s][1];
            sAlpha[s] = al;
        }
        __syncthreads();

        #pragma unroll
        for (int a2 = 0; a2 < 4; ++a2){
            float al[4];
            #pragma unroll
            for (int r = 0; r < 4; ++r) al[r] = sAlpha[16*a2 + quad*4 + r];
            #pragma unroll
            for (int bt = 0; bt < 4; ++bt)
                #pragma unroll
                for (int r = 0; r < 4; ++r) pacc[a2][bt][r] *= al[r];
        }

        for (int tsub = 0; tsub < 4; ++tsub){
            __syncthreads();
            #pragma unroll
            for (int p = 0; p < 4; ++p){
                int idx = p*256 + tid; int row = idx>>2, t8 = (idx&3)*8;
                *(f16x8*)&uKV[row*40 + t8] =
                    *(const f16x8*)(QVT + (size_t)row*S_ + t0 + tsub*32 + t8);
            }
            __syncthreads();
            f16x8 pa[4];
            #pragma unroll
            for (int a2 = 0; a2 < 4; ++a2)
                pa[a2] = *(const f16x8*)&sP[(16*a2+l15)*136 + tsub*32 + quad*8];
            #pragma unroll
            for (int bt = 0; bt < 4; ++bt){
                f16x8 qb = *(const f16x8*)&uKV[(wc+16*bt+l15)*40 + quad*8];
                #pragma unroll
                for (int a2 = 0; a2 < 4; ++a2)
                    pacc[a2][bt] = __builtin_amdgcn_mfma_f32_16x16x32_f16(pa[a2], qb, pacc[a2][bt], 0,0,0);
            }
        }
    }

    #pragma unroll
    for (int a2 = 0; a2 < 4; ++a2)
        #pragma unroll
        for (int r = 0; r < 4; ++r){
            int s = 16*a2 + quad*4 + r;
            float rl = 1.f / sState[s][1];
            #pragma unroll
            for (int bt = 0; bt < 4; ++bt){
                int c = wc + 16*bt + l15;
                outp[(size_t)(s0+s)*512 + c] = (f16)(pacc[a2][bt][r] * rl);
            }
        }
}

// ---------------------------------------------------------------------------
// 1x1 conv + bias + residual, f16 MFMA.
// D[o][s] = sum_i cwf[o][i] * cat[s][i] ; out = D + cb[o] + x[b][o][s]
// ---------------------------------------------------------------------------
__global__ __launch_bounds__(256) void k_conv(
    const f16* __restrict__ cat, const f16* __restrict__ cwf,
    const float* __restrict__ cb, const float* __restrict__ x,
    float* __restrict__ out)
{
    int b = blockIdx.z;
    int s0 = blockIdx.x*64, o0 = blockIdx.y*64;
    int tid = threadIdx.x, w = tid>>6, lane = tid&63, quad = lane>>4, l15 = lane&15;

    __shared__ __align__(16) f16 sA[64*72];   // cw tile [o][i-chunk]
    __shared__ __align__(16) f16 sB[64*72];   // cat tile [s][i-chunk]

    f32x4 D[4];
    #pragma unroll
    for (int i = 0; i < 4; ++i) D[i] = (f32x4){0.f,0.f,0.f,0.f};

    const f16* catb = cat + (size_t)b*S_*512;
    int row = tid>>2, c16 = (tid&3)*16;
    for (int i0 = 0; i0 < 512; i0 += 64){
        __syncthreads();
        *(f16x8*)&sA[row*72 + c16]     = *(const f16x8*)(cwf + (size_t)(o0+row)*512 + i0 + c16);
        *(f16x8*)&sA[row*72 + c16 + 8] = *(const f16x8*)(cwf + (size_t)(o0+row)*512 + i0 + c16 + 8);
        *(f16x8*)&sB[row*72 + c16]     = *(const f16x8*)(catb + (size_t)(s0+row)*512 + i0 + c16);
        *(f16x8*)&sB[row*72 + c16 + 8] = *(const f16x8*)(catb + (size_t)(s0+row)*512 + i0 + c16 + 8);
        __syncthreads();
        #pragma unroll
        for (int sub = 0; sub < 2; ++sub){
            f16x8 a = *(const f16x8*)&sA[(w*16+l15)*72 + sub*32 + quad*8];
            #pragma unroll
            for (int bt = 0; bt < 4; ++bt){
                f16x8 bb = *(const f16x8*)&sB[(bt*16+l15)*72 + sub*32 + quad*8];
                D[bt] = __builtin_amdgcn_mfma_f32_16x16x32_f16(a, bb, D[bt], 0,0,0);
            }
        }
    }
    // o_loc = w*16 + quad*4 + r ; s_loc = bt*16 + l15
    #pragma unroll
    for (int r = 0; r < 4; ++r){
        int o_loc = w*16 + quad*4 + r;
        float cbv = cb[o0 + o_loc];
        size_t base = (size_t)b*C_*S_ + (size_t)(o0+o_loc)*S_ + s0;
        #pragma unroll
        for (int bt = 0; bt < 4; ++bt){
            size_t a = base + bt*16 + l15;
            out[a] = D[bt][r] + cbv + x[a];
        }
    }
}

// ---------------------------------------------------------------------------
extern "C" void kernel_launch(void* const* d_in, const int* in_sizes, int n_in,
                              void* d_out, int out_size, void* d_ws, size_t ws_size,
                              hipStream_t stream)
{
    const float* lidar = (const float*)d_in[0];
    const float* hsi   = (const float*)d_in[1];
    const float* x     = (const float*)d_in[2];
    const float* Wq = (const float*)d_in[3];  const float* bq = (const float*)d_in[4];
    const float* Wk = (const float*)d_in[5];  const float* bk = (const float*)d_in[6];
    const float* Wv = (const float*)d_in[7];  const float* bv = (const float*)d_in[8];
    const float* cw = (const float*)d_in[9];  const float* cb = (const float*)d_in[10];
    const float* rw1 = (const float*)d_in[11]; const float* rb1 = (const float*)d_in[12];
    const float* rw2 = (const float*)d_in[13]; const float* rb2 = (const float*)d_in[14];
    float* outF = (float*)d_out;
    char* ws = (char*)d_ws;
    const size_t M = 1ull<<20;

    // ws map (f16 tensors are 16 MiB each = 32x1024x256):
    f16* lidT = (f16*)(ws +   0*M);   // alias: QVT1 after k_qkv
    f16* hsiT = (f16*)(ws +  16*M);   // alias: QVT2 after k_qkv
    f16* Qf_l = (f16*)(ws +  32*M);
    f16* Kf_l = (f16*)(ws +  48*M);
    f16* Qf_h = (f16*)(ws +  64*M);
    f16* Kf_h = (f16*)(ws +  80*M);
    f16* Qt_l = (f16*)(ws +  96*M);
    f16* Qt_h = (f16*)(ws + 112*M);
    f16* cat  = (f16*)(ws + 128*M);   // 32 MiB  [32][1024][512]
    float* g  = (float*)(ws + 160*M); // 64 KB
    f16* Wqf  = (f16*)(ws + 161*M);
    f16* Wkf  = (f16*)(ws + 161*M + 131072);
    f16* Wvf  = (f16*)(ws + 161*M + 262144);
    f16* cwf  = (f16*)(ws + 161*M + 393216);
    f16* QVT1 = lidT;
    f16* QVT2 = hsiT;
    // V temporaries live in d_out (dead until k_conv overwrites; path_prob at
    // byte 33,554,432 is just past Vt_h end — disjoint).
    f16* Vt_l = (f16*)d_out;
    f16* Vt_h = (f16*)d_out + 8388608;

    k_pool<<<4096, 256, 0, stream>>>(lidar, hsi, g);
    k_mlp<<<32, 256, 0, stream>>>(g, rw1, rb1, rw2, rb2, outF);
    k_cvtw<<<320, 256, 0, stream>>>(Wq, Wk, Wv, cw, Wqf, Wkf, Wvf, cwf);
    k_cvt<<<dim3(16,4,64), 256, 0, stream>>>(lidar, hsi, lidT, hsiT);
    k_qkv<<<dim3(16,4,192), 256, 0, stream>>>(lidT, hsiT, Wqf, Wkf, Wvf, bq, bk, bv,
                                              Qf_l, Kf_l, Qf_h, Kf_h, Qt_l, Qt_h, Vt_l, Vt_h);
    k_qv<<<4096, 256, 0, stream>>>(Qt_l, Qt_h, Vt_l, Vt_h, QVT1, QVT2);
    k_attn<<<dim3(16,64), 256, 0, stream>>>(Qf_l, Kf_l, Qf_h, Kf_h, QVT1, QVT2, cat);
    k_conv<<<dim3(16,4,32), 256, 0, stream>>>(cat, cwf, cb, x, outF);
}

// Round 5
// 407.370 us; speedup vs baseline: 8.2503x; 1.2593x over previous
//
#include <hip/hip_runtime.h>
#include <stdint.h>

typedef unsigned short u16;
typedef unsigned int u32;
typedef _Float16 f16;
typedef _Float16 f16x8 __attribute__((ext_vector_type(8)));
typedef _Float16 f16x4 __attribute__((ext_vector_type(4)));
typedef float f32x4 __attribute__((ext_vector_type(4)));

#define B_ 32
#define C_ 256
#define S_ 1024

// ---------------------------------------------------------------------------
// Router MLP: path_prob = sigmoid(relu((g/1024) W1^T + b1) W2^T + b2)
// g holds raw sums (scaled here). One block per b.
// ---------------------------------------------------------------------------
__global__ __launch_bounds__(256) void k_mlp(
    const float* __restrict__ g,
    const float* __restrict__ w1, const float* __restrict__ b1,
    const float* __restrict__ w2, const float* __restrict__ b2,
    float* __restrict__ out)
{
    int b = blockIdx.x, tid = threadIdx.x;
    __shared__ float sg[512];
    __shared__ float sh[128];
    sg[tid]     = g[b*512 + tid]       * (1.0f/1024.0f);
    sg[tid+256] = g[b*512 + 256 + tid] * (1.0f/1024.0f);
    __syncthreads();
    if (tid < 128){
        float a = b1[tid];
        const float* w = w1 + (size_t)tid*512;
        #pragma unroll 4
        for (int k = 0; k < 512; k += 4){
            float4 wv = *(const float4*)(w + k);
            a += sg[k]*wv.x + sg[k+1]*wv.y + sg[k+2]*wv.z + sg[k+3]*wv.w;
        }
        sh[tid] = fmaxf(a, 0.f);
    }
    __syncthreads();
    if (tid < 4){
        float a = b2[tid];
        const float* w = w2 + (size_t)tid*128;
        for (int k = 0; k < 128; ++k) a += sh[k]*w[k];
        out[(size_t)8388608 + b*4 + tid] = 1.f/(1.f+expf(-a));
    }
}

// ---------------------------------------------------------------------------
// Weight convert fp32 -> f16 (Wq, Wk, Wv 256x256 ; cw 256x512)
// ---------------------------------------------------------------------------
__global__ __launch_bounds__(256) void k_cvtw(
    const float* __restrict__ Wq, const float* __restrict__ Wk,
    const float* __restrict__ Wv, const float* __restrict__ cw,
    f16* __restrict__ Wqf, f16* __restrict__ Wkf,
    f16* __restrict__ Wvf, f16* __restrict__ cwf)
{
    int i = (blockIdx.x*256 + threadIdx.x) * 4;
    const float* src; f16* dst; int off;
    if (i < 65536){ src = Wq; dst = Wqf; off = i; }
    else if (i < 131072){ src = Wk; dst = Wkf; off = i - 65536; }
    else if (i < 196608){ src = Wv; dst = Wvf; off = i - 131072; }
    else { src = cw; dst = cwf; off = i - 196608; }
    float4 v = *(const float4*)(src + off);
    f16x4 r = { (f16)v.x, (f16)v.y, (f16)v.z, (f16)v.w };
    *(f16x4*)(dst + off) = r;
}

// ---------------------------------------------------------------------------
// Input convert+transpose fp32 [c][s] -> f16 [s][c]  + fused channel-mean pool
// pool: atomicAdd per (b, channel) of block-partial sums into g (pre-zeroed)
// ---------------------------------------------------------------------------
__global__ __launch_bounds__(256) void k_cvt(
    const float* __restrict__ lidar, const float* __restrict__ hsi,
    f16* __restrict__ lidT, f16* __restrict__ hsiT,
    float* __restrict__ g)
{
    int z = blockIdx.z, which = z >> 5, b = z & 31;
    const float* src = (which ? hsi : lidar) + (size_t)b*C_*S_;
    f16* dst = (which ? hsiT : lidT) + (size_t)b*S_*C_;
    int tid = threadIdx.x;
    int c4 = blockIdx.y*64 + (tid&15)*4;
    int s4 = blockIdx.x*64 + (tid>>4)*4;
    float4 m[4];
    #pragma unroll
    for (int r = 0; r < 4; ++r) m[r] = *(const float4*)(src + (size_t)(c4+r)*S_ + s4);
    f16x4 t0 = { (f16)m[0].x, (f16)m[1].x, (f16)m[2].x, (f16)m[3].x };
    f16x4 t1 = { (f16)m[0].y, (f16)m[1].y, (f16)m[2].y, (f16)m[3].y };
    f16x4 t2 = { (f16)m[0].z, (f16)m[1].z, (f16)m[2].z, (f16)m[3].z };
    f16x4 t3 = { (f16)m[0].w, (f16)m[1].w, (f16)m[2].w, (f16)m[3].w };
    *(f16x4*)(dst + (size_t)(s4+0)*C_ + c4) = t0;
    *(f16x4*)(dst + (size_t)(s4+1)*C_ + c4) = t1;
    *(f16x4*)(dst + (size_t)(s4+2)*C_ + c4) = t2;
    *(f16x4*)(dst + (size_t)(s4+3)*C_ + c4) = t3;
    // fused pool
    float ps[4];
    #pragma unroll
    for (int r = 0; r < 4; ++r){
        ps[r] = m[r].x + m[r].y + m[r].z + m[r].w;
        ps[r] += __shfl_xor(ps[r], 16, 64);
        ps[r] += __shfl_xor(ps[r], 32, 64);   // wave sum over its 16 s
    }
    __shared__ float sred[4][64];
    int wv = tid>>6, lane = tid&63;
    if ((lane>>4) == 0){
        #pragma unroll
        for (int r = 0; r < 4; ++r) sred[wv][(lane&15)*4 + r] = ps[r];
    }
    __syncthreads();
    if (tid < 64){
        float v = sred[0][tid] + sred[1][tid] + sred[2][tid] + sred[3][tid];
        atomicAdd(&g[b*512 + which*256 + blockIdx.y*64 + tid], v);
    }
}

// ---------------------------------------------------------------------------
// QKV projections, f16 MFMA.  combo: 0=Q_l 1=K_l 2=V_l 3=Q_h 4=K_h 5=V_h
// D[s][o] = sum_c In_t[s][c] * W[o][c] + bias[o]
// ---------------------------------------------------------------------------
__global__ __launch_bounds__(256) void k_qkv(
    const f16* __restrict__ lidT, const f16* __restrict__ hsiT,
    const f16* __restrict__ Wqf, const f16* __restrict__ Wkf, const f16* __restrict__ Wvf,
    const float* __restrict__ bq, const float* __restrict__ bk, const float* __restrict__ bv,
    f16* __restrict__ Qf_l, f16* __restrict__ Kf_l,
    f16* __restrict__ Qf_h, f16* __restrict__ Kf_h,
    f16* __restrict__ Qt_l, f16* __restrict__ Qt_h,
    f16* __restrict__ Vt_l, f16* __restrict__ Vt_h)
{
    int z = blockIdx.z, combo = z >> 5, b = z & 31, ww = combo % 3;
    const f16* In = ((combo < 3) ? lidT : hsiT) + (size_t)b*S_*C_;
    const f16* Wf = (ww==0) ? Wqf : (ww==1) ? Wkf : Wvf;
    const float* bias = (ww==0) ? bq : (ww==1) ? bk : bv;
    int s0 = blockIdx.x*64, o0 = blockIdx.y*64;
    int tid = threadIdx.x, w = tid>>6, lane = tid&63, quad = lane>>4, l15 = lane&15;

    __shared__ __align__(16) f16 sA[64*72];
    __shared__ __align__(16) f16 sB[64*72];

    f32x4 D[4];
    #pragma unroll
    for (int i = 0; i < 4; ++i) D[i] = (f32x4){0.f,0.f,0.f,0.f};

    int row = tid>>2, c16 = (tid&3)*16;
    for (int c0 = 0; c0 < 256; c0 += 64){
        __syncthreads();
        *(f16x8*)&sA[row*72 + c16]     = *(const f16x8*)(In + (size_t)(s0+row)*C_ + c0 + c16);
        *(f16x8*)&sA[row*72 + c16 + 8] = *(const f16x8*)(In + (size_t)(s0+row)*C_ + c0 + c16 + 8);
        *(f16x8*)&sB[row*72 + c16]     = *(const f16x8*)(Wf + (size_t)(o0+row)*C_ + c0 + c16);
        *(f16x8*)&sB[row*72 + c16 + 8] = *(const f16x8*)(Wf + (size_t)(o0+row)*C_ + c0 + c16 + 8);
        __syncthreads();
        #pragma unroll
        for (int sub = 0; sub < 2; ++sub){
            f16x8 a = *(const f16x8*)&sA[(w*16+l15)*72 + sub*32 + quad*8];
            #pragma unroll
            for (int bt = 0; bt < 4; ++bt){
                f16x8 bb = *(const f16x8*)&sB[(bt*16+l15)*72 + sub*32 + quad*8];
                D[bt] = __builtin_amdgcn_mfma_f32_16x16x32_f16(a, bb, D[bt], 0,0,0);
            }
        }
    }
    float bi[4];
    #pragma unroll
    for (int bt = 0; bt < 4; ++bt) bi[bt] = bias[o0 + bt*16 + l15];

    if (ww == 0){
        f16* F = ((combo==0) ? Qf_l : Qf_h) + (size_t)b*S_*C_;
        #pragma unroll
        for (int bt = 0; bt < 4; ++bt)
            #pragma unroll
            for (int r = 0; r < 4; ++r)
                F[(size_t)(s0 + w*16 + quad*4 + r)*C_ + o0 + bt*16 + l15] = (f16)(D[bt][r] + bi[bt]);
    } else if (ww == 1){
        f16* F = ((combo==1) ? Kf_l : Kf_h) + (size_t)b*S_*C_;
        #pragma unroll
        for (int bt = 0; bt < 4; ++bt)
            #pragma unroll
            for (int r = 0; r < 4; ++r)
                F[(size_t)(s0 + w*16 + quad*4 + r)*C_ + o0 + bt*16 + l15] = (f16)(D[bt][r] + bi[bt]);
    }
    if (ww != 1){
        __syncthreads();
        #pragma unroll
        for (int bt = 0; bt < 4; ++bt)
            #pragma unroll
            for (int r = 0; r < 4; ++r)
                sA[(bt*16+l15)*72 + w*16 + quad*4 + r] = (f16)(D[bt][r] + bi[bt]);
        __syncthreads();
        f16* T = (combo==0) ? Qt_l : (combo==3) ? Qt_h : (combo==2) ? Vt_l : Vt_h;
        T += (size_t)b*C_*S_;
        int o_r = tid>>2, s16b = (tid&3)*16;
        *(f16x8*)(T + (size_t)(o0+o_r)*S_ + s0 + s16b)     = *(const f16x8*)&sA[o_r*72 + s16b];
        *(f16x8*)(T + (size_t)(o0+o_r)*S_ + s0 + s16b + 8) = *(const f16x8*)&sA[o_r*72 + s16b + 8];
    }
}

// ---------------------------------------------------------------------------
// QVT1[c][s] = Qt_l*Vt_h ; QVT2[c][s] = Qt_h*Vt_l   (f16 elementwise)
// ---------------------------------------------------------------------------
__global__ __launch_bounds__(256) void k_qv(
    const f16* __restrict__ Qt_l, const f16* __restrict__ Qt_h,
    const f16* __restrict__ Vt_l, const f16* __restrict__ Vt_h,
    f16* __restrict__ QVT1, f16* __restrict__ QVT2)
{
    size_t idx = (size_t)(blockIdx.x*256 + threadIdx.x) * 8;
    f16x8 a = *(const f16x8*)(Qt_l+idx);
    f16x8 b = *(const f16x8*)(Vt_h+idx);
    *(f16x8*)(QVT1+idx) = a*b;
    f16x8 c = *(const f16x8*)(Qt_h+idx);
    f16x8 d = *(const f16x8*)(Vt_l+idx);
    *(f16x8*)(QVT2+idx) = c*d;
}

// ---------------------------------------------------------------------------
// MFMA flash attention, restructured:
//  - Q A-frags register-resident (loaded once)
//  - t-tile 64: sK + sQVT staged together -> 2 barriers per tt (32 total)
//  - wave-local online softmax (wave w owns q-rows 16w..16w+15); m/l/alpha in regs
//  - P D-layout -> A-frag via per-wave LDS scratch (no barrier)
// LDS 79.1 KB -> 2 blocks/CU.
// ---------------------------------------------------------------------------
__global__ __launch_bounds__(256, 2) void k_attn(
    const f16* __restrict__ Qf_l, const f16* __restrict__ Kf_l,
    const f16* __restrict__ Qf_h, const f16* __restrict__ Kf_h,
    const f16* __restrict__ QVT1, const f16* __restrict__ QVT2,
    f16* __restrict__ cat)
{
    int inst = blockIdx.y;
    int b = inst >> 1, which = inst & 1;
    const f16* Qf  = (which ? Qf_h : Qf_l) + (size_t)b*S_*C_;
    const f16* Kf  = (which ? Kf_h : Kf_l) + (size_t)b*S_*C_;
    const f16* QVT = (which ? QVT2 : QVT1) + (size_t)b*C_*S_;
    f16* outp = cat + (size_t)b*S_*512 + (which ? 0 : 256);
    int s0 = blockIdx.x*64;
    int tid = threadIdx.x, w = tid>>6, lane = tid&63, quad = lane>>4, l15 = lane&15;

    __shared__ __align__(16) f16 sK[64*264];    // [t][c] stride 264  (33792 B)
    __shared__ __align__(16) f16 sV[256*72];    // QVT [c][t64] stride 72 (36864 B)
    __shared__ __align__(16) f16 sPw[4][16*66]; // per-wave P scratch (8448 B)

    // Q A-frags in registers: wave w owns q-rows s0+16w .. s0+16w+15
    f16x8 qa[8];
    {
        const f16* qrow = Qf + (size_t)(s0 + w*16 + l15)*C_ + quad*8;
        #pragma unroll
        for (int i = 0; i < 8; ++i) qa[i] = *(const f16x8*)(qrow + i*32);
    }
    float mrun[4], lrun[4];
    #pragma unroll
    for (int r = 0; r < 4; ++r){ mrun[r] = -1e30f; lrun[r] = 0.f; }
    f32x4 pacc[16];
    #pragma unroll
    for (int i = 0; i < 16; ++i) pacc[i] = (f32x4){0.f,0.f,0.f,0.f};

    for (int tt = 0; tt < 16; ++tt){
        int t0 = tt*64;
        __syncthreads();
        #pragma unroll
        for (int p = 0; p < 8; ++p){      // stage K: 64 rows x 256 c
            int idx = p*256 + tid;
            int row = idx >> 5, c8 = (idx & 31)*8;
            *(f16x8*)&sK[row*264 + c8] = *(const f16x8*)(Kf + (size_t)(t0+row)*C_ + c8);
        }
        #pragma unroll
        for (int p = 0; p < 8; ++p){      // stage QVT: 256 rows x 64 t
            int idx = p*256 + tid;
            int row = idx >> 3, t8 = (idx & 7)*8;
            *(f16x8*)&sV[row*72 + t8] = *(const f16x8*)(QVT + (size_t)row*S_ + t0 + t8);
        }
        __syncthreads();

        // ---- scores: D[16 s][64 t] per wave ----
        f32x4 sacc[4];
        #pragma unroll
        for (int bt = 0; bt < 4; ++bt) sacc[bt] = (f32x4){0.f,0.f,0.f,0.f};
        #pragma unroll
        for (int ks = 0; ks < 8; ++ks){
            #pragma unroll
            for (int bt = 0; bt < 4; ++bt){
                f16x8 kb = *(const f16x8*)&sK[(bt*16+l15)*264 + ks*32 + quad*8];
                sacc[bt] = __builtin_amdgcn_mfma_f32_16x16x32_f16(qa[ks], kb, sacc[bt], 0,0,0);
            }
        }

        // ---- wave-local online softmax (rows s = quad*4 + r) ----
        float alpha[4], lsum[4];
        #pragma unroll
        for (int r = 0; r < 4; ++r){
            float tm = fmaxf(fmaxf(sacc[0][r], sacc[1][r]), fmaxf(sacc[2][r], sacc[3][r]));
            #pragma unroll
            for (int off = 1; off < 16; off <<= 1) tm = fmaxf(tm, __shfl_xor(tm, off, 64));
            float mn = fmaxf(mrun[r], tm);
            alpha[r] = __expf(mrun[r] - mn);
            mrun[r] = mn;
            float acc = 0.f;
            #pragma unroll
            for (int bt = 0; bt < 4; ++bt){
                float p = __expf(sacc[bt][r] - mn);
                sPw[w][(quad*4+r)*66 + bt*16 + l15] = (f16)p;
                acc += p;
            }
            #pragma unroll
            for (int off = 1; off < 16; off <<= 1) acc += __shfl_xor(acc, off, 64);
            lsum[r] = acc;
            lrun[r] = lrun[r]*alpha[r] + lsum[r];
        }
        // rescale accumulators
        #pragma unroll
        for (int cf = 0; cf < 16; ++cf)
            #pragma unroll
            for (int r = 0; r < 4; ++r) pacc[cf][r] *= alpha[r];

        // P A-frags (wave-internal LDS round-trip; no barrier)
        f16x8 pa0 = *(const f16x8*)&sPw[w][l15*66 + quad*8];
        f16x8 pa1 = *(const f16x8*)&sPw[w][l15*66 + 32 + quad*8];

        // ---- PV: D[16 s][256 c] per wave ----
        #pragma unroll
        for (int cf = 0; cf < 16; ++cf){
            f16x8 vb0 = *(const f16x8*)&sV[(cf*16+l15)*72 + quad*8];
            f16x8 vb1 = *(const f16x8*)&sV[(cf*16+l15)*72 + 32 + quad*8];
            pacc[cf] = __builtin_amdgcn_mfma_f32_16x16x32_f16(pa0, vb0, pacc[cf], 0,0,0);
            pacc[cf] = __builtin_amdgcn_mfma_f32_16x16x32_f16(pa1, vb1, pacc[cf], 0,0,0);
        }
    }

    // ---- epilogue ----
    #pragma unroll
    for (int r = 0; r < 4; ++r){
        int s = w*16 + quad*4 + r;
        float rl = 1.f / lrun[r];
        #pragma unroll
        for (int cf = 0; cf < 16; ++cf)
            outp[(size_t)(s0+s)*512 + cf*16 + l15] = (f16)(pacc[cf][r] * rl);
    }
}

// ---------------------------------------------------------------------------
// 1x1 conv + bias + residual, f16 MFMA
// ---------------------------------------------------------------------------
__global__ __launch_bounds__(256) void k_conv(
    const f16* __restrict__ cat, const f16* __restrict__ cwf,
    const float* __restrict__ cb, const float* __restrict__ x,
    float* __restrict__ out)
{
    int b = blockIdx.z;
    int s0 = blockIdx.x*64, o0 = blockIdx.y*64;
    int tid = threadIdx.x, w = tid>>6, lane = tid&63, quad = lane>>4, l15 = lane&15;

    __shared__ __align__(16) f16 sA[64*72];
    __shared__ __align__(16) f16 sB[64*72];

    f32x4 D[4];
    #pragma unroll
    for (int i = 0; i < 4; ++i) D[i] = (f32x4){0.f,0.f,0.f,0.f};

    const f16* catb = cat + (size_t)b*S_*512;
    int row = tid>>2, c16 = (tid&3)*16;
    for (int i0 = 0; i0 < 512; i0 += 64){
        __syncthreads();
        *(f16x8*)&sA[row*72 + c16]     = *(const f16x8*)(cwf + (size_t)(o0+row)*512 + i0 + c16);
        *(f16x8*)&sA[row*72 + c16 + 8] = *(const f16x8*)(cwf + (size_t)(o0+row)*512 + i0 + c16 + 8);
        *(f16x8*)&sB[row*72 + c16]     = *(const f16x8*)(catb + (size_t)(s0+row)*512 + i0 + c16);
        *(f16x8*)&sB[row*72 + c16 + 8] = *(const f16x8*)(catb + (size_t)(s0+row)*512 + i0 + c16 + 8);
        __syncthreads();
        #pragma unroll
        for (int sub = 0; sub < 2; ++sub){
            f16x8 a = *(const f16x8*)&sA[(w*16+l15)*72 + sub*32 + quad*8];
            #pragma unroll
            for (int bt = 0; bt < 4; ++bt){
                f16x8 bb = *(const f16x8*)&sB[(bt*16+l15)*72 + sub*32 + quad*8];
                D[bt] = __builtin_amdgcn_mfma_f32_16x16x32_f16(a, bb, D[bt], 0,0,0);
            }
        }
    }
    #pragma unroll
    for (int r = 0; r < 4; ++r){
        int o_loc = w*16 + quad*4 + r;
        float cbv = cb[o0 + o_loc];
        size_t base = (size_t)b*C_*S_ + (size_t)(o0+o_loc)*S_ + s0;
        #pragma unroll
        for (int bt = 0; bt < 4; ++bt){
            size_t a = base + bt*16 + l15;
            out[a] = D[bt][r] + cbv + x[a];
        }
    }
}

// ---------------------------------------------------------------------------
extern "C" void kernel_launch(void* const* d_in, const int* in_sizes, int n_in,
                              void* d_out, int out_size, void* d_ws, size_t ws_size,
                              hipStream_t stream)
{
    const float* lidar = (const float*)d_in[0];
    const float* hsi   = (const float*)d_in[1];
    const float* x     = (const float*)d_in[2];
    const float* Wq = (const float*)d_in[3];  const float* bq = (const float*)d_in[4];
    const float* Wk = (const float*)d_in[5];  const float* bk = (const float*)d_in[6];
    const float* Wv = (const float*)d_in[7];  const float* bv = (const float*)d_in[8];
    const float* cw = (const float*)d_in[9];  const float* cb = (const float*)d_in[10];
    const float* rw1 = (const float*)d_in[11]; const float* rb1 = (const float*)d_in[12];
    const float* rw2 = (const float*)d_in[13]; const float* rb2 = (const float*)d_in[14];
    float* outF = (float*)d_out;
    char* ws = (char*)d_ws;
    const size_t M = 1ull<<20;

    f16* lidT = (f16*)(ws +   0*M);   // alias: QVT1 after k_qkv
    f16* hsiT = (f16*)(ws +  16*M);   // alias: QVT2 after k_qkv
    f16* Qf_l = (f16*)(ws +  32*M);
    f16* Kf_l = (f16*)(ws +  48*M);
    f16* Qf_h = (f16*)(ws +  64*M);
    f16* Kf_h = (f16*)(ws +  80*M);
    f16* Qt_l = (f16*)(ws +  96*M);
    f16* Qt_h = (f16*)(ws + 112*M);
    f16* cat  = (f16*)(ws + 128*M);   // 32 MiB
    float* g  = (float*)(ws + 160*M); // 16 KB raw channel sums
    f16* Wqf  = (f16*)(ws + 161*M);
    f16* Wkf  = (f16*)(ws + 161*M + 131072);
    f16* Wvf  = (f16*)(ws + 161*M + 262144);
    f16* cwf  = (f16*)(ws + 161*M + 393216);
    f16* QVT1 = lidT;
    f16* QVT2 = hsiT;
    f16* Vt_l = (f16*)d_out;            // dead until k_conv; disjoint from path_prob
    f16* Vt_h = (f16*)d_out + 8388608;

    hipMemsetAsync(g, 0, 4096*sizeof(float), stream);
    k_cvtw<<<320, 256, 0, stream>>>(Wq, Wk, Wv, cw, Wqf, Wkf, Wvf, cwf);
    k_cvt<<<dim3(16,4,64), 256, 0, stream>>>(lidar, hsi, lidT, hsiT, g);
    k_mlp<<<32, 256, 0, stream>>>(g, rw1, rb1, rw2, rb2, outF);
    k_qkv<<<dim3(16,4,192), 256, 0, stream>>>(lidT, hsiT, Wqf, Wkf, Wvf, bq, bk, bv,
                                              Qf_l, Kf_l, Qf_h, Kf_h, Qt_l, Qt_h, Vt_l, Vt_h);
    k_qv<<<4096, 256, 0, stream>>>(Qt_l, Qt_h, Vt_l, Vt_h, QVT1, QVT2);
    k_attn<<<dim3(16,64), 256, 0, stream>>>(Qf_l, Kf_l, Qf_h, Kf_h, QVT1, QVT2, cat);
    k_conv<<<dim3(16,4,32), 256, 0, stream>>>(cat, cwf, cb, x, outF);
}